// Round 3
// baseline (8223.118 us; speedup 1.0000x reference)
//
#include <hip/hip_runtime.h>
#include <math.h>

#define PI_D 3.14159265358979323846264338327950288

enum { LOP_NONE=0, LOP_R2C, LOP_CENTER, LOP_ABSC, LOP_POWER, LOP_PAD };
enum { SOP_NONE=0, SOP_REAL };

// ---------------------------------------------------------------------------
// helpers
// ---------------------------------------------------------------------------
__host__ __device__ constexpr int P4(int a, int b){ return a*4 - a*(a-1)/2 + (b-a); }
__host__ __device__ constexpr int P5(int a, int b){ return a*5 - a*(a-1)/2 + (b-a); }

__device__ __forceinline__ unsigned encf(float f){
  unsigned u = __float_as_uint(f);
  return (u & 0x80000000u) ? ~u : (u | 0x80000000u);
}
__device__ __forceinline__ float decf(unsigned u){
  unsigned b = (u & 0x80000000u) ? (u ^ 0x80000000u) : ~u;
  return __uint_as_float(b);
}

template<int CNT>
__device__ __forceinline__ void wave_reduce_add(float (&acc)[CNT], double* out){
  int lane = threadIdx.x & 63;
  #pragma unroll
  for (int k = 0; k < CNT; k++){
    float v = acc[k];
    #pragma unroll
    for (int o = 32; o > 0; o >>= 1) v += __shfl_down(v, o, 64);
    if (lane == 0) atomicAdd(&out[k], (double)v);
  }
}

// polar grid of the ORIGINAL 1024x1024 image (0-indexed center at 512).
__device__ __forceinline__ void polar_at(int iy, int ix, double& lr, double& ang){
  double yn = (double)(iy - 512) / 512.0;
  double xn = (double)(ix - 512) / 512.0;
  ang = atan2(yn, xn);
  double rad = (iy == 512 && ix == 512) ? (1.0/512.0) : sqrt(xn*xn + yn*yn);
  lr = log2(rad);
}
__device__ __forceinline__ double d_hi(double lr, double shift){
  double v = lr - shift;
  v = fmin(fmax(v, -1.0), 0.0);
  return cos(PI_D * 0.5 * v);
}
__device__ __forceinline__ double d_lo(double lr, double shift){
  double h = d_hi(lr, shift);
  double q = 1.0 - h*h;
  q = fmin(fmax(q, 0.0), 1.0);
  return sqrt(q);
}

// ---------------------------------------------------------------------------
// FFT rows pass: one line per block, out-of-place capable, fused load-op.
// ---------------------------------------------------------------------------
template<int N>
__global__ __launch_bounds__((N/2 < 64) ? 64 : N/2)
void ps_fft_rows(float2* __restrict__ dst, const void* __restrict__ vsrc,
                 const double* __restrict__ msum, float invn,
                 int simg, int dimg, int srcH1,
                 float dir, int xin, int xout, int lop)
{
  constexpr int T = (N/2 < 64) ? 64 : N/2;
  __shared__ float2 smem[2*N];
  float2* sA = smem; float2* sB = smem + N;
  const int t = threadIdx.x;
  const int l = blockIdx.x & (N-1);
  const int img = blockIdx.x / N;
  float2* dline = dst + (size_t)img*(size_t)dimg + (size_t)l*N;

  if (lop == LOP_PAD){
    const int q = N/4;
    const int sl = l - q;
    if (sl < 0 || sl >= srcH1){
      for (int j = t; j < N; j += T) dline[j] = make_float2(0.f, 0.f);
      return;
    }
    const float2* s = (const float2*)vsrc + (size_t)img*simg + (size_t)sl*srcH1;
    for (int j = t; j < N; j += T){
      int p = j ^ xin;
      sA[j] = (p >= q && p < q + srcH1) ? s[p - q] : make_float2(0.f, 0.f);
    }
  } else if (lop == LOP_R2C){
    const float* s = (const float*)vsrc + (size_t)img*simg + (size_t)l*N;
    for (int j = t; j < N; j += T) sA[j] = make_float2(s[j ^ xin], 0.f);
  } else if (lop == LOP_CENTER){
    const float* s = (const float*)vsrc + (size_t)img*simg + (size_t)l*N;
    float m = (float)(msum[img] * (double)invn);
    for (int j = t; j < N; j += T) sA[j] = make_float2(s[j ^ xin] - m, 0.f);
  } else if (lop == LOP_ABSC){
    const float2* s = (const float2*)vsrc + (size_t)img*simg + (size_t)l*N;
    float m = (float)(msum[img] * (double)invn);
    for (int j = t; j < N; j += T){
      float2 v = s[j ^ xin];
      sA[j] = make_float2(sqrtf(v.x*v.x + v.y*v.y) - m, 0.f);
    }
  } else if (lop == LOP_POWER){
    const float2* s = (const float2*)vsrc + (size_t)img*simg + (size_t)l*N;
    for (int j = t; j < N; j += T){
      float2 v = s[j ^ xin];
      sA[j] = make_float2(v.x*v.x + v.y*v.y, 0.f);
    }
  } else {
    const float2* s = (const float2*)vsrc + (size_t)img*simg + (size_t)l*N;
    for (int j = t; j < N; j += T) sA[j] = s[j ^ xin];
  }
  __syncthreads();
  float2* src = sA; float2* dstp = sB;
  for (int Ns = 1; Ns < N; Ns <<= 1){
    if (t < N/2){
      int k = t & (Ns - 1);
      float2 i0 = src[t], i1 = src[t + N/2];
      float ang = dir * (float)PI_D * (float)k / (float)Ns;
      float sw, cw; sincosf(ang, &sw, &cw);
      float2 tv = make_float2(cw*i1.x - sw*i1.y, cw*i1.y + sw*i1.x);
      int d = ((t - k) << 1) + k;
      dstp[d]      = make_float2(i0.x + tv.x, i0.y + tv.y);
      dstp[d + Ns] = make_float2(i0.x - tv.x, i0.y - tv.y);
    }
    __syncthreads();
    float2* tmp = src; src = dstp; dstp = tmp;
  }
  for (int j = t; j < N; j += T) dline[j ^ xout] = src[j];
}

// ---------------------------------------------------------------------------
// FFT cols pass: CB adjacent columns per block (coalesced), in-place,
// optional real store with scale.
// ---------------------------------------------------------------------------
template<int N, int CB>
__global__ __launch_bounds__(512)
void ps_fft_cols(float2* __restrict__ buf, int bimg,
                 float dir, int xin, int xout, float scale,
                 int sop, float* __restrict__ rdst, int rimg)
{
  constexpr int T = 512;
  constexpr int LCB = (CB==2)?1:(CB==4)?2:(CB==8)?3:4;
  constexpr int NB = N / CB;
  __shared__ float2 smem[2*N*CB];
  float2* sA = smem; float2* sB = smem + N*CB;
  const int t = threadIdx.x;
  const int img = blockIdx.x / NB;
  const int c0 = (blockIdx.x % NB) * CB;
  float2* b = buf + (size_t)img*(size_t)bimg + c0;

  for (int e = t; e < N*CB; e += T){
    int j = e >> LCB, c = e & (CB - 1);
    sA[j*CB + c] = b[(size_t)(j ^ xin)*N + c];
  }
  __syncthreads();
  float2* src = sA; float2* dstp = sB;
  for (int Ns = 1; Ns < N; Ns <<= 1){
    for (int q = t; q < (N/2)*CB; q += T){
      int c  = q & (CB - 1);
      int tt = q >> LCB;
      int k  = tt & (Ns - 1);
      float2 i0 = src[tt*CB + c], i1 = src[(tt + N/2)*CB + c];
      float ang = dir * (float)PI_D * (float)k / (float)Ns;
      float sw, cw; sincosf(ang, &sw, &cw);
      float2 tv = make_float2(cw*i1.x - sw*i1.y, cw*i1.y + sw*i1.x);
      int d = ((tt - k) << 1) + k;
      dstp[d*CB + c]        = make_float2(i0.x + tv.x, i0.y + tv.y);
      dstp[(d + Ns)*CB + c] = make_float2(i0.x - tv.x, i0.y - tv.y);
    }
    __syncthreads();
    float2* tmp = src; src = dstp; dstp = tmp;
  }
  if (sop == SOP_REAL){
    for (int e = t; e < N*CB; e += T){
      int j = e >> LCB, c = e & (CB - 1);
      rdst[(size_t)img*(size_t)rimg + (size_t)(j ^ xout)*N + c0 + c] = src[j*CB + c].x * scale;
    }
  } else {
    for (int e = t; e < N*CB; e += T){
      int j = e >> LCB, c = e & (CB - 1);
      float2 v = src[j*CB + c];
      b[(size_t)(j ^ xout)*N + c] = make_float2(v.x*scale, v.y*scale);
    }
  }
}

// ---------------------------------------------------------------------------
// elementwise kernels
// ---------------------------------------------------------------------------
__global__ __launch_bounds__(256)
void ps_mask_hl(float2* __restrict__ lo_dst, float2* __restrict__ hi_dst,
                const float2* __restrict__ src){
  int i = blockIdx.x*blockDim.x + threadIdx.x;
  if (i >= 1024*1024) return;
  int y = i >> 10, x = i & 1023;
  double lr, ang; polar_at(y, x, lr, ang);
  float2 v = src[i];
  float lo = (float)d_lo(lr, 0.0), hi = (float)d_hi(lr, 0.0);
  lo_dst[i] = make_float2(v.x*lo, v.y*lo);
  hi_dst[i] = make_float2(v.x*hi, v.y*hi);
}
__global__ __launch_bounds__(256)
void ps_band_mask4(float2* __restrict__ dst, const float2* __restrict__ src,
                   int H, int off, double shift){
  int i = blockIdx.x*blockDim.x + threadIdx.x;
  int n = H*H;
  if (i >= n) return;
  int y = i / H, x = i - y*H;
  double lr, ang; polar_at(off + y, off + x, lr, ang);
  double hm = d_hi(lr, shift);
  float2 v = src[i];
  #pragma unroll
  for (int b = 0; b < 4; b++){
    double a0 = ang - PI_D*(double)b/4.0 + PI_D;
    double a = fmod(a0, 2.0*PI_D);
    if (a < 0.0) a += 2.0*PI_D;
    a -= PI_D;
    double mk = 0.0;
    if (fabs(a) < PI_D*0.5){ double c = cos(a); mk = 2.0*sqrt(0.8)*c*c*c; }
    float mf = (float)(hm*mk);
    dst[(size_t)b*n + i] = make_float2(-mf*v.y, mf*v.x);
  }
}
__global__ __launch_bounds__(256)
void ps_crop_lo(float2* dst, const float2* src, int Hs, int offNew, double shift){
  int Hd = Hs/2;
  int i = blockIdx.x*blockDim.x + threadIdx.x;
  if (i >= Hd*Hd) return;
  int y = i / Hd, x = i - y*Hd;
  double lr, ang; polar_at(offNew + y, offNew + x, lr, ang);
  float mk = (float)d_lo(lr, shift);
  float2 v = src[(y + Hs/4)*Hs + (x + Hs/4)];
  dst[i] = make_float2(v.x*mk, v.y*mk);
}
__global__ __launch_bounds__(128)
void ps_extract_ac(float* __restrict__ out, const float2* __restrict__ ac,
                   int n_per_img, int H, int base0, int img_mul, int stride){
  int img = blockIdx.x;
  int t = threadIdx.x;           // 81 threads
  if (t >= 81) return;
  int dy = t / 9, dx = t - dy*9;
  const float2* a = ac + (size_t)img * (size_t)n_per_img;
  float inv = 1.0f / ((float)H * (float)H);
  float ctr = a[0].x * inv;
  int Y = (H/2 - 4 + dy) ^ (H/2);
  int X = (H/2 - 4 + dx) ^ (H/2);
  float v = a[(size_t)Y*H + X].x * inv;
  out[base0 + img*img_mul + (dy*9 + dx)*stride] = v / (ctr + 1e-12f);
}

// ---------------------------------------------------------------------------
// reductions  (all __launch_bounds__(256) — without it hipcc caps VGPRs for a
// hypothetical 1024-thread block and SPILLS the accumulator arrays to scratch:
// round-2 rocprof showed ps_scaleB at 1690us/dispatch, VALUBusy 1.6%, VGPR=60)
// ---------------------------------------------------------------------------
__global__ void ps_init_mm(unsigned* mm){ mm[0] = 0xFFFFFFFFu; mm[1] = 0u; }

__global__ __launch_bounds__(256)
void ps_moments(const float* x, int n, double* out){
  float acc[4] = {0.f,0.f,0.f,0.f};
  for (int i = blockIdx.x*blockDim.x + threadIdx.x; i < n; i += gridDim.x*blockDim.x){
    float v = x[i], v2 = v*v;
    acc[0] += v; acc[1] += v2; acc[2] += v2*v; acc[3] += v2*v2;
  }
  wave_reduce_add<4>(acc, out);
}
__global__ __launch_bounds__(256)
void ps_sumabs(const float* x, int n, double* out){
  float acc[1] = {0.f};
  for (int i = blockIdx.x*blockDim.x + threadIdx.x; i < n; i += gridDim.x*blockDim.x)
    acc[0] += fabsf(x[i]);
  wave_reduce_add<1>(acc, out);
}
__global__ __launch_bounds__(256)
void ps_minmax(const float* x, int n, unsigned* mm){
  unsigned mn = 0xFFFFFFFFu, mx = 0u;
  for (int i = blockIdx.x*blockDim.x + threadIdx.x; i < n; i += gridDim.x*blockDim.x){
    unsigned e = encf(x[i]);
    mn = (e < mn) ? e : mn;
    mx = (e > mx) ? e : mx;
  }
  #pragma unroll
  for (int o = 32; o > 0; o >>= 1){
    unsigned a = __shfl_down(mn, o, 64); if (a < mn) mn = a;
    unsigned b = __shfl_down(mx, o, 64); if (b > mx) mx = b;
  }
  if ((threadIdx.x & 63) == 0){ atomicMin(&mm[0], mn); atomicMax(&mm[1], mx); }
}
__global__ __launch_bounds__(256)
void ps_hipass_stats(const float2* h, int n, double* out){
  float acc[3] = {0.f,0.f,0.f};
  for (int i = blockIdx.x*blockDim.x + threadIdx.x; i < n; i += gridDim.x*blockDim.x){
    float v = h[i].x;
    acc[0] += v; acc[1] += v*v; acc[2] += fabsf(v);
  }
  wave_reduce_add<3>(acc, out);
}
__global__ __launch_bounds__(256)
void ps_scaleA(const float2* __restrict__ b0, const float2* __restrict__ b1,
               const float2* __restrict__ b2, const float2* __restrict__ b3,
               int n, double* out){
  float acc[28];
  #pragma unroll
  for (int k = 0; k < 28; k++) acc[k] = 0.f;
  for (int i = blockIdx.x*blockDim.x + threadIdx.x; i < n; i += gridDim.x*blockDim.x){
    float2 v0 = b0[i], v1 = b1[i], v2 = b2[i], v3 = b3[i];
    float ab[4] = { sqrtf(v0.x*v0.x+v0.y*v0.y), sqrtf(v1.x*v1.x+v1.y*v1.y),
                    sqrtf(v2.x*v2.x+v2.y*v2.y), sqrtf(v3.x*v3.x+v3.y*v3.y) };
    float re[4] = { v0.x, v1.x, v2.x, v3.x };
    #pragma unroll
    for (int a = 0; a < 4; a++){
      #pragma unroll
      for (int c = a; c < 4; c++){
        acc[P4(a,c)]      += ab[a]*ab[c];
        acc[10 + P4(a,c)] += re[a]*re[c];
      }
      acc[20 + a] += ab[a];
      acc[24 + a] += re[a];
    }
  }
  wave_reduce_add<28>(acc, out);
}
__global__ __launch_bounds__(256)
void ps_scaleB(const float2* __restrict__ u0, const float2* __restrict__ u1,
               const float2* __restrict__ u2, const float2* __restrict__ u3,
               const float2* __restrict__ s0, const float2* __restrict__ s1,
               const float2* __restrict__ s2, const float2* __restrict__ s3,
               int n, double* out){
  float acc[72];
  #pragma unroll
  for (int k = 0; k < 72; k++) acc[k] = 0.f;
  for (int i = blockIdx.x*blockDim.x + threadIdx.x; i < n; i += gridDim.x*blockDim.x){
    float2 u[4] = { u0[i], u1[i], u2[i], u3[i] };
    float2 bb[4] = { s0[i], s1[i], s2[i], s3[i] };
    float au[4], dre[4], dim[4], M[4], R[4];
    #pragma unroll
    for (int c = 0; c < 4; c++){
      float xx = u[c].x, yy = u[c].y;
      float mag = sqrtf(xx*xx + yy*yy);
      float den = mag + 1e-12f;
      au[c] = mag;
      dre[c] = (xx*xx - yy*yy)/den;
      dim[c] = (2.f*xx*yy)/den;
      M[c] = sqrtf(bb[c].x*bb[c].x + bb[c].y*bb[c].y);
      R[c] = bb[c].x;
    }
    #pragma unroll
    for (int c = 0; c < 4; c++){
      acc[c]      += au[c];
      acc[4 + c]  += au[c]*au[c];
      acc[24 + c] += dre[c];
      acc[28 + c] += dim[c];
      acc[32 + c] += dre[c]*dre[c];
      acc[36 + c] += dim[c]*dim[c];
    }
    #pragma unroll
    for (int a = 0; a < 4; a++)
      #pragma unroll
      for (int c = 0; c < 4; c++){
        acc[8 + a*4 + c]  += M[a]*au[c];
        acc[40 + a*4 + c] += R[a]*dre[c];
        acc[56 + a*4 + c] += R[a]*dim[c];
      }
  }
  wave_reduce_add<72>(acc, out);
}
__global__ __launch_bounds__(256)
void ps_scaleC(const float2* __restrict__ s0, const float2* __restrict__ s1,
               const float2* __restrict__ s2, const float2* __restrict__ s3,
               const float* __restrict__ lp, int n, double* out){
  float acc[36];
  #pragma unroll
  for (int k = 0; k < 36; k++) acc[k] = 0.f;
  for (int i = blockIdx.x*blockDim.x + threadIdx.x; i < n; i += gridDim.x*blockDim.x){
    int y = i >> 7, x = i & 127;
    float L[5];
    L[0] = lp[i];
    L[1] = lp[(y << 7) | ((x + 126) & 127)];
    L[2] = lp[(y << 7) | ((x + 2) & 127)];
    L[3] = lp[(((y + 126) & 127) << 7) | x];
    L[4] = lp[(((y + 2) & 127) << 7) | x];
    float R[4] = { s0[i].x, s1[i].x, s2[i].x, s3[i].x };
    acc[0] += L[0];
    #pragma unroll
    for (int a = 0; a < 5; a++)
      #pragma unroll
      for (int c = a; c < 5; c++)
        acc[1 + P5(a,c)] += L[a]*L[c];
    #pragma unroll
    for (int a = 0; a < 4; a++)
      #pragma unroll
      for (int j = 0; j < 5; j++)
        acc[16 + a*5 + j] += R[a]*L[j];
  }
  wave_reduce_add<36>(acc, out);
}

// ---------------------------------------------------------------------------
// finalize (single thread, doubles)
// ---------------------------------------------------------------------------
__global__ void ps_finalize(const double* __restrict__ ST, const unsigned* __restrict__ MM,
                            float* __restrict__ out){
  if (threadIdx.x != 0 || blockIdx.x != 0) return;
  const double n0 = 1048576.0;
  {
    double m = ST[0]/n0, e2 = ST[1]/n0, e3 = ST[2]/n0, e4 = ST[3]/n0;
    double v = e2 - m*m;
    double c3 = e3 - 3.0*m*e2 + 2.0*m*m*m;
    double c4 = e4 - 4.0*m*e3 + 6.0*m*m*e2 - 3.0*m*m*m*m;
    out[0] = (float)m; out[1] = (float)v;
    out[2] = (float)(c3/pow(v,1.5)); out[3] = (float)(c4/(v*v));
    out[4] = decf(MM[0]); out[5] = decf(MM[1]);
    out[6] = (float)(ST[6]/n0);
    out[23] = (float)(ST[28]/4096.0);
    out[2460] = (float)(ST[5]/n0 - (ST[4]/n0)*(ST[4]/n0));
  }
  for (int s = 0; s < 4; s++){
    double ns = (double)(1024 >> s) * (double)(1024 >> s);
    for (int b = 0; b < 4; b++)
      out[7 + s*4 + b] = (float)(ST[64 + s*32 + 20 + b]/ns);
  }
  for (int r = 0; r < 5; r++){
    double nr = (double)(1024 >> r) * (double)(1024 >> r);
    if (r == 4) nr = 4096.0;
    const double* Mo = ST + 8 + r*4;
    double m = Mo[0]/nr, e2 = Mo[1]/nr, e3 = Mo[2]/nr, e4 = Mo[3]/nr;
    double v = e2 - m*m;
    double c3 = e3 - 3.0*m*e2 + 2.0*m*m*m;
    double c4 = e4 - 4.0*m*e3 + 6.0*m*m*e2 - 3.0*m*m*m*m;
    out[1320 + r] = (float)(c3/pow(v,1.5));
    out[1325 + r] = (float)(c4/(v*v));
    out[1735 + r] = (float)sqrt(v);
  }
  for (int s = 0; s < 4; s++){
    double ns = (double)(1024 >> s) * (double)(1024 >> s);
    const double* A = ST + 64 + s*32;
    double mM[4], mR[4], sdM[4], sdR[4], cM[4][4], cR[4][4];
    for (int a = 0; a < 4; a++){ mM[a] = A[20+a]/ns; mR[a] = A[24+a]/ns; }
    for (int a = 0; a < 4; a++)
      for (int b = a; b < 4; b++){
        double vM = A[P4(a,b)]/ns - mM[a]*mM[b];
        double vR = A[10 + P4(a,b)]/ns - mR[a]*mR[b];
        cM[a][b] = cM[b][a] = vM;
        cR[a][b] = cR[b][a] = vR;
      }
    for (int a = 0; a < 4; a++){ sdM[a] = sqrt(cM[a][a]); sdR[a] = sqrt(cR[a][a]); }
    for (int a = 0; a < 4; a++)
      for (int b = 0; b < 4; b++){
        out[1740 + (a*4 + b)*5 + s] = (float)(cM[a][b]/(sdM[a]*sdM[b] + 1e-12));
        out[1884 + (a*8 + b)*5 + s] = (float)(cR[a][b]/(sdR[a]*sdR[b] + 1e-12));
      }
    if (s < 3){
      const double* B = ST + 192 + s*80;
      double mU[4], sdU[4], mdr[4], mdi[4], sdr[4], sdi[4];
      for (int c = 0; c < 4; c++){
        mU[c] = B[c]/ns;       sdU[c] = sqrt(B[4+c]/ns - mU[c]*mU[c]);
        mdr[c] = B[24+c]/ns;   mdi[c] = B[28+c]/ns;
        sdr[c] = sqrt(B[32+c]/ns - mdr[c]*mdr[c]);
        sdi[c] = sqrt(B[36+c]/ns - mdi[c]*mdi[c]);
      }
      for (int a = 0; a < 4; a++)
        for (int c = 0; c < 4; c++){
          out[1820 + (a*4 + c)*4 + s] =
            (float)((B[8 + a*4 + c]/ns - mM[a]*mU[c])/(sdM[a]*sdU[c] + 1e-12));
          out[2204 + (a*8 + c)*4 + s] =
            (float)((B[40 + a*4 + c]/ns - mR[a]*mdr[c])/(sdR[a]*sdr[c] + 1e-12));
          out[2204 + (a*8 + 4 + c)*4 + s] =
            (float)((B[56 + a*4 + c]/ns - mR[a]*mdi[c])/(sdR[a]*sdi[c] + 1e-12));
        }
    } else {
      const double* C = ST + 432;
      const double n3 = 16384.0;
      double lb = C[0]/n3;
      double cL[5][5], sdL[5];
      for (int i = 0; i < 5; i++)
        for (int j = i; j < 5; j++){
          double v = C[1 + P5(i,j)]/n3 - lb*lb;
          cL[i][j] = cL[j][i] = v;
        }
      for (int i = 0; i < 5; i++) sdL[i] = sqrt(cL[i][i]);
      for (int a = 0; a < 4; a++)
        for (int j = 0; j < 5; j++)
          out[2204 + (a*8 + j)*4 + 3] =
            (float)((C[16 + a*5 + j]/n3 - mR[a]*lb)/(sdR[a]*sdL[j] + 1e-12));
      for (int i = 0; i < 5; i++)
        for (int j = 0; j < 5; j++)
          out[1884 + (i*8 + j)*5 + 4] = (float)(cL[i][j]/(sdL[i]*sdL[j] + 1e-12));
    }
  }
}

// ---------------------------------------------------------------------------
// host orchestration
// ---------------------------------------------------------------------------
static void rows_pass(int H, float2* dst, const void* src,
                      const double* msum, float invn,
                      int nimg, int simg, int dimg, int srcH1,
                      float dir, int xin, int xout, int lop, hipStream_t st){
  dim3 g(nimg * H);
  switch (H){
    case 64:   ps_fft_rows<64>  <<<g, 64,  0, st>>>(dst, src, msum, invn, simg, dimg, srcH1, dir, xin, xout, lop); break;
    case 128:  ps_fft_rows<128> <<<g, 64,  0, st>>>(dst, src, msum, invn, simg, dimg, srcH1, dir, xin, xout, lop); break;
    case 256:  ps_fft_rows<256> <<<g, 128, 0, st>>>(dst, src, msum, invn, simg, dimg, srcH1, dir, xin, xout, lop); break;
    case 512:  ps_fft_rows<512> <<<g, 256, 0, st>>>(dst, src, msum, invn, simg, dimg, srcH1, dir, xin, xout, lop); break;
    case 1024: ps_fft_rows<1024><<<g, 512, 0, st>>>(dst, src, msum, invn, simg, dimg, srcH1, dir, xin, xout, lop); break;
    default: break;
  }
}
static void cols_pass(int H, float2* buf, int nimg, int bimg,
                      float dir, int xin, int xout, float scale,
                      int sop, float* rdst, int rimg, hipStream_t st){
  switch (H){
    case 64:   ps_fft_cols<64,16>  <<<dim3(nimg*(64/16)),   512, 0, st>>>(buf, bimg, dir, xin, xout, scale, sop, rdst, rimg); break;
    case 128:  ps_fft_cols<128,16> <<<dim3(nimg*(128/16)),  512, 0, st>>>(buf, bimg, dir, xin, xout, scale, sop, rdst, rimg); break;
    case 256:  ps_fft_cols<256,8>  <<<dim3(nimg*(256/8)),   512, 0, st>>>(buf, bimg, dir, xin, xout, scale, sop, rdst, rimg); break;
    case 512:  ps_fft_cols<512,8>  <<<dim3(nimg*(512/8)),   512, 0, st>>>(buf, bimg, dir, xin, xout, scale, sop, rdst, rimg); break;
    case 1024: ps_fft_cols<1024,4> <<<dim3(nimg*(1024/4)),  512, 0, st>>>(buf, bimg, dir, xin, xout, scale, sop, rdst, rimg); break;
    default: break;
  }
}

static inline dim3 gr(int n){ return dim3((n + 255)/256); }
static inline int  rblocks(int n){ int b = (n + 255)/256; return b > 2048 ? 2048 : b; }

#define FWD (-1.0f)
#define INV (+1.0f)

extern "C" void kernel_launch(void* const* d_in, const int* in_sizes, int n_in,
                              void* d_out, int out_size, void* d_ws, size_t ws_size,
                              hipStream_t stream){
  (void)in_sizes; (void)n_in;
  const float* im = (const float*)d_in[0];
  float* out = (float*)d_out;

  const int Hs[5]   = {1024, 512, 256, 128, 64};
  const int offs[5] = {0, 256, 384, 448, 480};

  // ---- carve workspace ----
  char* base = (char*)d_ws;
  size_t off = 0;
  auto carve = [&](size_t bytes)->void*{
    void* r = base + off;
    off = (off + bytes + 255) & ~(size_t)255;
    return r;
  };
  float2* lod[5];
  for (int s = 0; s < 5; s++) lod[s] = (float2*)carve((size_t)Hs[s]*Hs[s]*sizeof(float2));
  float2* band[4];
  for (int s = 0; s < 4; s++) band[s] = (float2*)carve((size_t)4*Hs[s]*Hs[s]*sizeof(float2));
  float* recon[5];
  for (int s = 0; s < 5; s++) recon[s] = (float*)carve((size_t)Hs[s]*Hs[s]*sizeof(float));
  float* lp = (float*)carve(128*128*sizeof(float));
  float2* scr  = (float2*)carve((size_t)1024*1024*sizeof(float2));
  float2* scr4 = (float2*)carve((size_t)4*1024*1024*sizeof(float2));
  double* ST = (double*)carve(512*sizeof(double));
  unsigned* MM = (unsigned*)carve(64*sizeof(unsigned));
  if (off > ws_size) return;

  // ---- init ----
  hipMemsetAsync(out, 0, (size_t)out_size*sizeof(float), stream);
  hipMemsetAsync(ST, 0, 512*sizeof(double), stream);
  ps_init_mm<<<1, 1, 0, stream>>>(MM);

  const int n0 = 1024*1024;
  ps_moments<<<rblocks(n0), 256, 0, stream>>>(im, n0, ST + 0);
  ps_minmax <<<rblocks(n0), 256, 0, stream>>>(im, n0, MM);

  // ---- imdft (shifted) ----
  rows_pass(1024, scr, im, nullptr, 0.f, 1, 0, 0, 0, FWD, 0, 512, LOP_R2C, stream);
  cols_pass(1024, scr, 1, 0, FWD, 0, 512, 1.0f, SOP_NONE, nullptr, 0, stream);
  ps_mask_hl<<<gr(n0), 256, 0, stream>>>(lod[0], scr, scr);
  rows_pass(1024, scr, scr, nullptr, 0.f, 1, 0, 0, 0, INV, 512, 0, LOP_NONE, stream);
  cols_pass(1024, scr, 1, 0, INV, 512, 0, 1.0f/(float)n0, SOP_NONE, nullptr, 0, stream);
  ps_hipass_stats<<<rblocks(n0), 256, 0, stream>>>(scr, n0, ST + 4);

  // ---- pyramid scales ----
  for (int s = 0; s < 4; s++){
    int H = Hs[s], n = H*H;
    float invn = 1.0f/((float)H*(float)H);
    rows_pass(H, scr, lod[s], nullptr, 0.f, 1, 0, 0, 0, INV, H/2, 0, LOP_NONE, stream);
    cols_pass(H, scr, 1, 0, INV, H/2, 0, invn, SOP_REAL, recon[s], 0, stream);
    ps_band_mask4<<<gr(n), 256, 0, stream>>>(band[s], lod[s], H, offs[s], -(double)(s+1));
    rows_pass(H, band[s], band[s], nullptr, 0.f, 4, n, n, 0, INV, H/2, 0, LOP_NONE, stream);
    cols_pass(H, band[s], 4, n, INV, H/2, 0, invn, SOP_NONE, nullptr, 0, stream);
    ps_crop_lo<<<gr((H/2)*(H/2)), 256, 0, stream>>>(lod[s+1], lod[s], H, offs[s+1], -(double)(s+1));
  }
  rows_pass(64, scr, lod[4], nullptr, 0.f, 1, 0, 0, 0, INV, 32, 0, LOP_NONE, stream);
  cols_pass(64, scr, 1, 0, INV, 32, 0, 1.0f/4096.f, SOP_REAL, recon[4], 0, stream);

  // ---- recon moments + autocorrs ----
  for (int r = 0; r < 5; r++){
    int H = Hs[r], n = H*H;
    float invn = 1.0f/(float)n;
    ps_moments<<<rblocks(n), 256, 0, stream>>>(recon[r], n, ST + 8 + r*4);
    rows_pass(H, scr, recon[r], ST + 8 + r*4, invn, 1, 0, 0, 0, FWD, 0, 0, LOP_CENTER, stream);
    cols_pass(H, scr, 1, 0, FWD, 0, 0, 1.0f, SOP_NONE, nullptr, 0, stream);
    rows_pass(H, scr, scr, nullptr, 0.f, 1, 0, 0, 0, INV, 0, 0, LOP_POWER, stream);
    cols_pass(H, scr, 1, 0, INV, 0, 0, invn, SOP_NONE, nullptr, 0, stream);
    ps_extract_ac<<<1, 128, 0, stream>>>(out, scr, 0, H, 1330 + r, 0, 5);
  }
  ps_sumabs<<<rblocks(4096), 256, 0, stream>>>(recon[4], 4096, ST + 28);

  // ---- per-scale band Grams ----
  for (int s = 0; s < 4; s++){
    int n = Hs[s]*Hs[s];
    ps_scaleA<<<rblocks(n), 256, 0, stream>>>(band[s], band[s]+n, band[s]+2*n, band[s]+3*n,
                                              n, ST + 64 + s*32);
  }

  // ---- cross-scale ----
  for (int s = 0; s < 3; s++){
    int H1 = Hs[s+1], H2 = Hs[s];
    int n1 = H1*H1, n2 = H2*H2;
    rows_pass(H1, scr, band[s+1], nullptr, 0.f, 4, n1, n1, 0, FWD, 0, H1/2, LOP_NONE, stream);
    cols_pass(H1, scr, 4, n1, FWD, 0, H1/2, 1.0f, SOP_NONE, nullptr, 0, stream);
    rows_pass(H2, scr4, scr, nullptr, 0.f, 4, n1, n2, H1, INV, H2/2, 0, LOP_PAD, stream);
    cols_pass(H2, scr4, 4, n2, INV, H2/2, 0, 1.0f/(float)n1, SOP_NONE, nullptr, 0, stream);
    ps_scaleB<<<rblocks(n2), 256, 0, stream>>>(scr4, scr4+n2, scr4+2*n2, scr4+3*n2,
                                               band[s], band[s]+n2, band[s]+2*n2, band[s]+3*n2,
                                               n2, ST + 192 + s*80);
  }
  // s=3: expand2(lowpass)
  rows_pass(64, scr, recon[4], nullptr, 0.f, 1, 0, 0, 0, FWD, 0, 32, LOP_R2C, stream);
  cols_pass(64, scr, 1, 0, FWD, 0, 32, 1.0f, SOP_NONE, nullptr, 0, stream);
  rows_pass(128, scr4, scr, nullptr, 0.f, 1, 4096, 16384, 64, INV, 64, 0, LOP_PAD, stream);
  cols_pass(128, scr4, 1, 0, INV, 64, 0, 1.0f/4096.f, SOP_REAL, lp, 0, stream);
  ps_scaleC<<<rblocks(16384), 256, 0, stream>>>(band[3], band[3]+16384, band[3]+2*16384, band[3]+3*16384,
                                                lp, 16384, ST + 432);

  // ---- band-magnitude autocorrs ----
  for (int s = 0; s < 4; s++){
    int H = Hs[s], n = H*H;
    float invn = 1.0f/(float)n;
    rows_pass(H, scr4, band[s], ST + 64 + s*32 + 20, invn, 4, n, n, 0, FWD, 0, 0, LOP_ABSC, stream);
    cols_pass(H, scr4, 4, n, FWD, 0, 0, 1.0f, SOP_NONE, nullptr, 0, stream);
    rows_pass(H, scr4, scr4, nullptr, 0.f, 4, n, n, 0, INV, 0, 0, LOP_POWER, stream);
    cols_pass(H, scr4, 4, n, INV, 0, 0, invn, SOP_NONE, nullptr, 0, stream);
    ps_extract_ac<<<4, 128, 0, stream>>>(out, scr4, n, H, 24 + s*4, 1, 16);
  }

  // ---- finalize ----
  ps_finalize<<<1, 1, 0, stream>>>(ST, MM, out);
}

// Round 4
// 1042.481 us; speedup vs baseline: 7.8880x; 7.8880x over previous
//
#include <hip/hip_runtime.h>
#include <math.h>

#define PI_D 3.14159265358979323846264338327950288

enum { LOP_NONE=0, LOP_R2C, LOP_CENTER, LOP_ABSC, LOP_POWER, LOP_PAD };
enum { SOP_NONE=0, SOP_REAL };

// ---------------------------------------------------------------------------
// helpers
// ---------------------------------------------------------------------------
__host__ __device__ constexpr int P4(int a, int b){ return a*4 - a*(a-1)/2 + (b-a); }
__host__ __device__ constexpr int P5(int a, int b){ return a*5 - a*(a-1)/2 + (b-a); }

__device__ __forceinline__ unsigned encf(float f){
  unsigned u = __float_as_uint(f);
  return (u & 0x80000000u) ? ~u : (u | 0x80000000u);
}
__device__ __forceinline__ float decf(unsigned u){
  unsigned b = (u & 0x80000000u) ? (u ^ 0x80000000u) : ~u;
  return __uint_as_float(b);
}

// block = 256 threads (4 waves). Wave shuffle-reduce -> LDS -> ONE atomicAdd
// per counter per block. (Round-3 lesson: per-wave atomics = 590K same-line
// f64 atomics on scaleB = 1.7ms serialized.)
template<int CNT>
__device__ __forceinline__ void block_reduce_add(float (&acc)[CNT], double* out){
  __shared__ float red[4*CNT];
  int lane = threadIdx.x & 63;
  int wid  = threadIdx.x >> 6;
  #pragma unroll
  for (int k = 0; k < CNT; k++){
    float v = acc[k];
    #pragma unroll
    for (int o = 32; o > 0; o >>= 1) v += __shfl_down(v, o, 64);
    if (lane == 0) red[wid*CNT + k] = v;
  }
  __syncthreads();
  int t = threadIdx.x;
  if (t < CNT){
    double s = (double)red[t] + (double)red[CNT+t] + (double)red[2*CNT+t] + (double)red[3*CNT+t];
    atomicAdd(&out[t], s);
  }
}

// polar grid of the ORIGINAL 1024x1024 image (0-indexed center at 512).
__device__ __forceinline__ void polar_at(int iy, int ix, double& lr, double& ang){
  double yn = (double)(iy - 512) / 512.0;
  double xn = (double)(ix - 512) / 512.0;
  ang = atan2(yn, xn);
  double rad = (iy == 512 && ix == 512) ? (1.0/512.0) : sqrt(xn*xn + yn*yn);
  lr = log2(rad);
}
__device__ __forceinline__ double d_hi(double lr, double shift){
  double v = lr - shift;
  v = fmin(fmax(v, -1.0), 0.0);
  return cos(PI_D * 0.5 * v);
}
__device__ __forceinline__ double d_lo(double lr, double shift){
  double h = d_hi(lr, shift);
  double q = 1.0 - h*h;
  q = fmin(fmax(q, 0.0), 1.0);
  return sqrt(q);
}

// ---------------------------------------------------------------------------
// FFT rows pass: one line per block, out-of-place capable, fused load-op.
// ---------------------------------------------------------------------------
template<int N>
__global__ __launch_bounds__((N/2 < 64) ? 64 : N/2)
void ps_fft_rows(float2* __restrict__ dst, const void* __restrict__ vsrc,
                 const double* __restrict__ msum, float invn,
                 int simg, int dimg, int srcH1,
                 float dir, int xin, int xout, int lop)
{
  constexpr int T = (N/2 < 64) ? 64 : N/2;
  __shared__ float2 smem[2*N];
  float2* sA = smem; float2* sB = smem + N;
  const int t = threadIdx.x;
  const int l = blockIdx.x & (N-1);
  const int img = blockIdx.x / N;
  float2* dline = dst + (size_t)img*(size_t)dimg + (size_t)l*N;

  if (lop == LOP_PAD){
    const int q = N/4;
    const int sl = l - q;
    if (sl < 0 || sl >= srcH1){
      for (int j = t; j < N; j += T) dline[j] = make_float2(0.f, 0.f);
      return;
    }
    const float2* s = (const float2*)vsrc + (size_t)img*simg + (size_t)sl*srcH1;
    for (int j = t; j < N; j += T){
      int p = j ^ xin;
      sA[j] = (p >= q && p < q + srcH1) ? s[p - q] : make_float2(0.f, 0.f);
    }
  } else if (lop == LOP_R2C){
    const float* s = (const float*)vsrc + (size_t)img*simg + (size_t)l*N;
    for (int j = t; j < N; j += T) sA[j] = make_float2(s[j ^ xin], 0.f);
  } else if (lop == LOP_CENTER){
    const float* s = (const float*)vsrc + (size_t)img*simg + (size_t)l*N;
    float m = (float)(msum[img] * (double)invn);
    for (int j = t; j < N; j += T) sA[j] = make_float2(s[j ^ xin] - m, 0.f);
  } else if (lop == LOP_ABSC){
    const float2* s = (const float2*)vsrc + (size_t)img*simg + (size_t)l*N;
    float m = (float)(msum[img] * (double)invn);
    for (int j = t; j < N; j += T){
      float2 v = s[j ^ xin];
      sA[j] = make_float2(sqrtf(v.x*v.x + v.y*v.y) - m, 0.f);
    }
  } else if (lop == LOP_POWER){
    const float2* s = (const float2*)vsrc + (size_t)img*simg + (size_t)l*N;
    for (int j = t; j < N; j += T){
      float2 v = s[j ^ xin];
      sA[j] = make_float2(v.x*v.x + v.y*v.y, 0.f);
    }
  } else {
    const float2* s = (const float2*)vsrc + (size_t)img*simg + (size_t)l*N;
    for (int j = t; j < N; j += T) sA[j] = s[j ^ xin];
  }
  __syncthreads();
  float2* src = sA; float2* dstp = sB;
  for (int Ns = 1; Ns < N; Ns <<= 1){
    if (t < N/2){
      int k = t & (Ns - 1);
      float2 i0 = src[t], i1 = src[t + N/2];
      float ang = dir * (float)PI_D * (float)k / (float)Ns;
      float sw, cw; __sincosf(ang, &sw, &cw);
      float2 tv = make_float2(cw*i1.x - sw*i1.y, cw*i1.y + sw*i1.x);
      int d = ((t - k) << 1) + k;
      dstp[d]      = make_float2(i0.x + tv.x, i0.y + tv.y);
      dstp[d + Ns] = make_float2(i0.x - tv.x, i0.y - tv.y);
    }
    __syncthreads();
    float2* tmp = src; src = dstp; dstp = tmp;
  }
  for (int j = t; j < N; j += T) dline[j ^ xout] = src[j];
}

// ---------------------------------------------------------------------------
// FFT cols pass: CB adjacent columns per block (coalesced), in-place,
// optional POWER on load, optional real store with scale.
// ---------------------------------------------------------------------------
template<int N, int CB>
__global__ __launch_bounds__(512)
void ps_fft_cols(float2* __restrict__ buf, int bimg,
                 float dir, int xin, int xout, float scale,
                 int sop, float* __restrict__ rdst, int rimg, int lop)
{
  constexpr int T = 512;
  constexpr int LCB = (CB==2)?1:(CB==4)?2:(CB==8)?3:4;
  constexpr int NB = N / CB;
  __shared__ float2 smem[2*N*CB];
  float2* sA = smem; float2* sB = smem + N*CB;
  const int t = threadIdx.x;
  const int img = blockIdx.x / NB;
  const int c0 = (blockIdx.x % NB) * CB;
  float2* b = buf + (size_t)img*(size_t)bimg + c0;

  for (int e = t; e < N*CB; e += T){
    int j = e >> LCB, c = e & (CB - 1);
    float2 v = b[(size_t)(j ^ xin)*N + c];
    if (lop == LOP_POWER) v = make_float2(v.x*v.x + v.y*v.y, 0.f);
    sA[j*CB + c] = v;
  }
  __syncthreads();
  float2* src = sA; float2* dstp = sB;
  for (int Ns = 1; Ns < N; Ns <<= 1){
    for (int q = t; q < (N/2)*CB; q += T){
      int c  = q & (CB - 1);
      int tt = q >> LCB;
      int k  = tt & (Ns - 1);
      float2 i0 = src[tt*CB + c], i1 = src[(tt + N/2)*CB + c];
      float ang = dir * (float)PI_D * (float)k / (float)Ns;
      float sw, cw; __sincosf(ang, &sw, &cw);
      float2 tv = make_float2(cw*i1.x - sw*i1.y, cw*i1.y + sw*i1.x);
      int d = ((tt - k) << 1) + k;
      dstp[d*CB + c]        = make_float2(i0.x + tv.x, i0.y + tv.y);
      dstp[(d + Ns)*CB + c] = make_float2(i0.x - tv.x, i0.y - tv.y);
    }
    __syncthreads();
    float2* tmp = src; src = dstp; dstp = tmp;
  }
  if (sop == SOP_REAL){
    for (int e = t; e < N*CB; e += T){
      int j = e >> LCB, c = e & (CB - 1);
      rdst[(size_t)img*(size_t)rimg + (size_t)(j ^ xout)*N + c0 + c] = src[j*CB + c].x * scale;
    }
  } else {
    for (int e = t; e < N*CB; e += T){
      int j = e >> LCB, c = e & (CB - 1);
      float2 v = src[j*CB + c];
      b[(size_t)(j ^ xout)*N + c] = make_float2(v.x*scale, v.y*scale);
    }
  }
}

// ---------------------------------------------------------------------------
// autocorr tail: inverse-FFT ONLY the 9 needed rows (after full col inverse),
// write the 81 normalized outputs directly. ctr = E[x^2]-m^2 via Parseval
// from already-accumulated sums (s1 = sum x, s2 = sum x^2).
// ---------------------------------------------------------------------------
template<int N>
__global__ __launch_bounds__((N/2 < 64) ? 64 : N/2)
void ps_ac_rows(float* __restrict__ out, const float2* __restrict__ buf, int n_per_img,
                const double* __restrict__ s1, const double* __restrict__ s2, int sstride,
                double nrecip, float invn2, int base0, int img_mul, int stride)
{
  constexpr int T = (N/2 < 64) ? 64 : N/2;
  __shared__ float2 smem[2*N];
  float2* sA = smem; float2* sB = smem + N;
  const int t = threadIdx.x;
  const int img = blockIdx.x / 9;
  const int dy  = blockIdx.x % 9;
  const int row = (dy - 4) & (N - 1);
  const float2* line = buf + (size_t)img*(size_t)n_per_img + (size_t)row*N;
  for (int j = t; j < N; j += T) sA[j] = line[j];
  __syncthreads();
  float2* src = sA; float2* dstp = sB;
  for (int Ns = 1; Ns < N; Ns <<= 1){
    if (t < N/2){
      int k = t & (Ns - 1);
      float2 i0 = src[t], i1 = src[t + N/2];
      float ang = (float)PI_D * (float)k / (float)Ns;   // inverse
      float sw, cw; __sincosf(ang, &sw, &cw);
      float2 tv = make_float2(cw*i1.x - sw*i1.y, cw*i1.y + sw*i1.x);
      int d = ((t - k) << 1) + k;
      dstp[d]      = make_float2(i0.x + tv.x, i0.y + tv.y);
      dstp[d + Ns] = make_float2(i0.x - tv.x, i0.y - tv.y);
    }
    __syncthreads();
    float2* tmp = src; src = dstp; dstp = tmp;
  }
  if (t < 9){
    int col = (t - 4) & (N - 1);
    double m = s1[img*sstride] * nrecip;
    double ctr = s2[img*sstride] * nrecip - m*m;
    float v = src[col].x * invn2;
    out[base0 + img*img_mul + (dy*9 + t)*stride] = v / ((float)ctr + 1e-12f);
  }
}

// ---------------------------------------------------------------------------
// elementwise kernels
// ---------------------------------------------------------------------------
__global__ __launch_bounds__(256)
void ps_mask_hl(float2* __restrict__ lo_dst, float2* __restrict__ hi_dst,
                const float2* __restrict__ src){
  int i = blockIdx.x*blockDim.x + threadIdx.x;
  if (i >= 1024*1024) return;
  int y = i >> 10, x = i & 1023;
  double lr, ang; polar_at(y, x, lr, ang);
  float2 v = src[i];
  float lo = (float)d_lo(lr, 0.0), hi = (float)d_hi(lr, 0.0);
  lo_dst[i] = make_float2(v.x*lo, v.y*lo);
  hi_dst[i] = make_float2(v.x*hi, v.y*hi);
}
__global__ __launch_bounds__(256)
void ps_band_mask4(float2* __restrict__ dst, const float2* __restrict__ src,
                   int H, int off, double shift){
  int i = blockIdx.x*blockDim.x + threadIdx.x;
  int n = H*H;
  if (i >= n) return;
  int y = i / H, x = i - y*H;
  double lr, ang; polar_at(off + y, off + x, lr, ang);
  double hm = d_hi(lr, shift);
  float2 v = src[i];
  #pragma unroll
  for (int b = 0; b < 4; b++){
    double a0 = ang - PI_D*(double)b/4.0 + PI_D;
    double a = fmod(a0, 2.0*PI_D);
    if (a < 0.0) a += 2.0*PI_D;
    a -= PI_D;
    double mk = 0.0;
    if (fabs(a) < PI_D*0.5){ double c = cos(a); mk = 2.0*sqrt(0.8)*c*c*c; }
    float mf = (float)(hm*mk);
    dst[(size_t)b*n + i] = make_float2(-mf*v.y, mf*v.x);
  }
}
__global__ __launch_bounds__(256)
void ps_crop_lo(float2* dst, const float2* src, int Hs, int offNew, double shift){
  int Hd = Hs/2;
  int i = blockIdx.x*blockDim.x + threadIdx.x;
  if (i >= Hd*Hd) return;
  int y = i / Hd, x = i - y*Hd;
  double lr, ang; polar_at(offNew + y, offNew + x, lr, ang);
  float mk = (float)d_lo(lr, shift);
  float2 v = src[(y + Hs/4)*Hs + (x + Hs/4)];
  dst[i] = make_float2(v.x*mk, v.y*mk);
}

// ---------------------------------------------------------------------------
// reductions (256 threads/block, block_reduce_add; (256,1) bounds so the
// accumulator arrays stay in VGPRs instead of spilling)
// ---------------------------------------------------------------------------
__global__ void ps_init_mm(unsigned* mm){ mm[0] = 0xFFFFFFFFu; mm[1] = 0u; }

__global__ __launch_bounds__(256, 1)
void ps_moments(const float* x, int n, double* out){
  float acc[4] = {0.f,0.f,0.f,0.f};
  for (int i = blockIdx.x*blockDim.x + threadIdx.x; i < n; i += gridDim.x*blockDim.x){
    float v = x[i], v2 = v*v;
    acc[0] += v; acc[1] += v2; acc[2] += v2*v; acc[3] += v2*v2;
  }
  block_reduce_add<4>(acc, out);
}
__global__ __launch_bounds__(256, 1)
void ps_sumabs(const float* x, int n, double* out){
  float acc[1] = {0.f};
  for (int i = blockIdx.x*blockDim.x + threadIdx.x; i < n; i += gridDim.x*blockDim.x)
    acc[0] += fabsf(x[i]);
  block_reduce_add<1>(acc, out);
}
__global__ __launch_bounds__(256, 1)
void ps_minmax(const float* x, int n, unsigned* mm){
  unsigned mn = 0xFFFFFFFFu, mx = 0u;
  for (int i = blockIdx.x*blockDim.x + threadIdx.x; i < n; i += gridDim.x*blockDim.x){
    unsigned e = encf(x[i]);
    mn = (e < mn) ? e : mn;
    mx = (e > mx) ? e : mx;
  }
  #pragma unroll
  for (int o = 32; o > 0; o >>= 1){
    unsigned a = __shfl_down(mn, o, 64); if (a < mn) mn = a;
    unsigned b = __shfl_down(mx, o, 64); if (b > mx) mx = b;
  }
  if ((threadIdx.x & 63) == 0){ atomicMin(&mm[0], mn); atomicMax(&mm[1], mx); }
}
__global__ __launch_bounds__(256, 1)
void ps_hipass_stats(const float2* h, int n, double* out){
  float acc[3] = {0.f,0.f,0.f};
  for (int i = blockIdx.x*blockDim.x + threadIdx.x; i < n; i += gridDim.x*blockDim.x){
    float v = h[i].x;
    acc[0] += v; acc[1] += v*v; acc[2] += fabsf(v);
  }
  block_reduce_add<3>(acc, out);
}
// out: gramM[10], gramR[10], sum|b|[4], sumRe[4], sum|b|^2 diag[4]  (32 total)
__global__ __launch_bounds__(256, 1)
void ps_scaleA(const float2* __restrict__ b0, const float2* __restrict__ b1,
               const float2* __restrict__ b2, const float2* __restrict__ b3,
               int n, double* out){
  float acc[32];
  #pragma unroll
  for (int k = 0; k < 32; k++) acc[k] = 0.f;
  for (int i = blockIdx.x*blockDim.x + threadIdx.x; i < n; i += gridDim.x*blockDim.x){
    float2 v0 = b0[i], v1 = b1[i], v2 = b2[i], v3 = b3[i];
    float ab[4] = { sqrtf(v0.x*v0.x+v0.y*v0.y), sqrtf(v1.x*v1.x+v1.y*v1.y),
                    sqrtf(v2.x*v2.x+v2.y*v2.y), sqrtf(v3.x*v3.x+v3.y*v3.y) };
    float re[4] = { v0.x, v1.x, v2.x, v3.x };
    #pragma unroll
    for (int a = 0; a < 4; a++){
      #pragma unroll
      for (int c = a; c < 4; c++){
        acc[P4(a,c)]      += ab[a]*ab[c];
        acc[10 + P4(a,c)] += re[a]*re[c];
      }
      acc[20 + a] += ab[a];
      acc[24 + a] += re[a];
      acc[28 + a] += ab[a]*ab[a];
    }
  }
  block_reduce_add<32>(acc, out);
}
__global__ __launch_bounds__(256, 1)
void ps_scaleB(const float2* __restrict__ u0, const float2* __restrict__ u1,
               const float2* __restrict__ u2, const float2* __restrict__ u3,
               const float2* __restrict__ s0, const float2* __restrict__ s1,
               const float2* __restrict__ s2, const float2* __restrict__ s3,
               int n, double* out){
  float acc[72];
  #pragma unroll
  for (int k = 0; k < 72; k++) acc[k] = 0.f;
  for (int i = blockIdx.x*blockDim.x + threadIdx.x; i < n; i += gridDim.x*blockDim.x){
    float2 u[4] = { u0[i], u1[i], u2[i], u3[i] };
    float2 bb[4] = { s0[i], s1[i], s2[i], s3[i] };
    float au[4], dre[4], dim[4], M[4], R[4];
    #pragma unroll
    for (int c = 0; c < 4; c++){
      float xx = u[c].x, yy = u[c].y;
      float mag = sqrtf(xx*xx + yy*yy);
      float den = mag + 1e-12f;
      au[c] = mag;
      dre[c] = (xx*xx - yy*yy)/den;
      dim[c] = (2.f*xx*yy)/den;
      M[c] = sqrtf(bb[c].x*bb[c].x + bb[c].y*bb[c].y);
      R[c] = bb[c].x;
    }
    #pragma unroll
    for (int c = 0; c < 4; c++){
      acc[c]      += au[c];
      acc[4 + c]  += au[c]*au[c];
      acc[24 + c] += dre[c];
      acc[28 + c] += dim[c];
      acc[32 + c] += dre[c]*dre[c];
      acc[36 + c] += dim[c]*dim[c];
    }
    #pragma unroll
    for (int a = 0; a < 4; a++)
      #pragma unroll
      for (int c = 0; c < 4; c++){
        acc[8 + a*4 + c]  += M[a]*au[c];
        acc[40 + a*4 + c] += R[a]*dre[c];
        acc[56 + a*4 + c] += R[a]*dim[c];
      }
  }
  block_reduce_add<72>(acc, out);
}
__global__ __launch_bounds__(256, 1)
void ps_scaleC(const float2* __restrict__ s0, const float2* __restrict__ s1,
               const float2* __restrict__ s2, const float2* __restrict__ s3,
               const float* __restrict__ lp, int n, double* out){
  float acc[36];
  #pragma unroll
  for (int k = 0; k < 36; k++) acc[k] = 0.f;
  for (int i = blockIdx.x*blockDim.x + threadIdx.x; i < n; i += gridDim.x*blockDim.x){
    int y = i >> 7, x = i & 127;
    float L[5];
    L[0] = lp[i];
    L[1] = lp[(y << 7) | ((x + 126) & 127)];
    L[2] = lp[(y << 7) | ((x + 2) & 127)];
    L[3] = lp[(((y + 126) & 127) << 7) | x];
    L[4] = lp[(((y + 2) & 127) << 7) | x];
    float R[4] = { s0[i].x, s1[i].x, s2[i].x, s3[i].x };
    acc[0] += L[0];
    #pragma unroll
    for (int a = 0; a < 5; a++)
      #pragma unroll
      for (int c = a; c < 5; c++)
        acc[1 + P5(a,c)] += L[a]*L[c];
    #pragma unroll
    for (int a = 0; a < 4; a++)
      #pragma unroll
      for (int j = 0; j < 5; j++)
        acc[16 + a*5 + j] += R[a]*L[j];
  }
  block_reduce_add<36>(acc, out);
}

// ---------------------------------------------------------------------------
// finalize (single thread, doubles)
// ---------------------------------------------------------------------------
__global__ void ps_finalize(const double* __restrict__ ST, const unsigned* __restrict__ MM,
                            float* __restrict__ out){
  if (threadIdx.x != 0 || blockIdx.x != 0) return;
  const double n0 = 1048576.0;
  {
    double m = ST[0]/n0, e2 = ST[1]/n0, e3 = ST[2]/n0, e4 = ST[3]/n0;
    double v = e2 - m*m;
    double c3 = e3 - 3.0*m*e2 + 2.0*m*m*m;
    double c4 = e4 - 4.0*m*e3 + 6.0*m*m*e2 - 3.0*m*m*m*m;
    out[0] = (float)m; out[1] = (float)v;
    out[2] = (float)(c3/pow(v,1.5)); out[3] = (float)(c4/(v*v));
    out[4] = decf(MM[0]); out[5] = decf(MM[1]);
    out[6] = (float)(ST[6]/n0);
    out[23] = (float)(ST[28]/4096.0);
    out[2460] = (float)(ST[5]/n0 - (ST[4]/n0)*(ST[4]/n0));
  }
  for (int s = 0; s < 4; s++){
    double ns = (double)(1024 >> s) * (double)(1024 >> s);
    for (int b = 0; b < 4; b++)
      out[7 + s*4 + b] = (float)(ST[64 + s*32 + 20 + b]/ns);
  }
  for (int r = 0; r < 5; r++){
    double nr = (double)(1024 >> r) * (double)(1024 >> r);
    if (r == 4) nr = 4096.0;
    const double* Mo = ST + 8 + r*4;
    double m = Mo[0]/nr, e2 = Mo[1]/nr, e3 = Mo[2]/nr, e4 = Mo[3]/nr;
    double v = e2 - m*m;
    double c3 = e3 - 3.0*m*e2 + 2.0*m*m*m;
    double c4 = e4 - 4.0*m*e3 + 6.0*m*m*e2 - 3.0*m*m*m*m;
    out[1320 + r] = (float)(c3/pow(v,1.5));
    out[1325 + r] = (float)(c4/(v*v));
    out[1735 + r] = (float)sqrt(v);
  }
  for (int s = 0; s < 4; s++){
    double ns = (double)(1024 >> s) * (double)(1024 >> s);
    const double* A = ST + 64 + s*32;
    double mM[4], mR[4], sdM[4], sdR[4], cM[4][4], cR[4][4];
    for (int a = 0; a < 4; a++){ mM[a] = A[20+a]/ns; mR[a] = A[24+a]/ns; }
    for (int a = 0; a < 4; a++)
      for (int b = a; b < 4; b++){
        double vM = A[P4(a,b)]/ns - mM[a]*mM[b];
        double vR = A[10 + P4(a,b)]/ns - mR[a]*mR[b];
        cM[a][b] = cM[b][a] = vM;
        cR[a][b] = cR[b][a] = vR;
      }
    for (int a = 0; a < 4; a++){ sdM[a] = sqrt(cM[a][a]); sdR[a] = sqrt(cR[a][a]); }
    for (int a = 0; a < 4; a++)
      for (int b = 0; b < 4; b++){
        out[1740 + (a*4 + b)*5 + s] = (float)(cM[a][b]/(sdM[a]*sdM[b] + 1e-12));
        out[1884 + (a*8 + b)*5 + s] = (float)(cR[a][b]/(sdR[a]*sdR[b] + 1e-12));
      }
    if (s < 3){
      const double* B = ST + 192 + s*80;
      double mU[4], sdU[4], mdr[4], mdi[4], sdr[4], sdi[4];
      for (int c = 0; c < 4; c++){
        mU[c] = B[c]/ns;       sdU[c] = sqrt(B[4+c]/ns - mU[c]*mU[c]);
        mdr[c] = B[24+c]/ns;   mdi[c] = B[28+c]/ns;
        sdr[c] = sqrt(B[32+c]/ns - mdr[c]*mdr[c]);
        sdi[c] = sqrt(B[36+c]/ns - mdi[c]*mdi[c]);
      }
      for (int a = 0; a < 4; a++)
        for (int c = 0; c < 4; c++){
          out[1820 + (a*4 + c)*4 + s] =
            (float)((B[8 + a*4 + c]/ns - mM[a]*mU[c])/(sdM[a]*sdU[c] + 1e-12));
          out[2204 + (a*8 + c)*4 + s] =
            (float)((B[40 + a*4 + c]/ns - mR[a]*mdr[c])/(sdR[a]*sdr[c] + 1e-12));
          out[2204 + (a*8 + 4 + c)*4 + s] =
            (float)((B[56 + a*4 + c]/ns - mR[a]*mdi[c])/(sdR[a]*sdi[c] + 1e-12));
        }
    } else {
      const double* C = ST + 432;
      const double n3 = 16384.0;
      double lb = C[0]/n3;
      double cL[5][5], sdL[5];
      for (int i = 0; i < 5; i++)
        for (int j = i; j < 5; j++){
          double v = C[1 + P5(i,j)]/n3 - lb*lb;
          cL[i][j] = cL[j][i] = v;
        }
      for (int i = 0; i < 5; i++) sdL[i] = sqrt(cL[i][i]);
      for (int a = 0; a < 4; a++)
        for (int j = 0; j < 5; j++)
          out[2204 + (a*8 + j)*4 + 3] =
            (float)((C[16 + a*5 + j]/n3 - mR[a]*lb)/(sdR[a]*sdL[j] + 1e-12));
      for (int i = 0; i < 5; i++)
        for (int j = 0; j < 5; j++)
          out[1884 + (i*8 + j)*5 + 4] = (float)(cL[i][j]/(sdL[i]*sdL[j] + 1e-12));
    }
  }
}

// ---------------------------------------------------------------------------
// host orchestration
// ---------------------------------------------------------------------------
static void rows_pass(int H, float2* dst, const void* src,
                      const double* msum, float invn,
                      int nimg, int simg, int dimg, int srcH1,
                      float dir, int xin, int xout, int lop, hipStream_t st){
  dim3 g(nimg * H);
  switch (H){
    case 64:   ps_fft_rows<64>  <<<g, 64,  0, st>>>(dst, src, msum, invn, simg, dimg, srcH1, dir, xin, xout, lop); break;
    case 128:  ps_fft_rows<128> <<<g, 64,  0, st>>>(dst, src, msum, invn, simg, dimg, srcH1, dir, xin, xout, lop); break;
    case 256:  ps_fft_rows<256> <<<g, 128, 0, st>>>(dst, src, msum, invn, simg, dimg, srcH1, dir, xin, xout, lop); break;
    case 512:  ps_fft_rows<512> <<<g, 256, 0, st>>>(dst, src, msum, invn, simg, dimg, srcH1, dir, xin, xout, lop); break;
    case 1024: ps_fft_rows<1024><<<g, 512, 0, st>>>(dst, src, msum, invn, simg, dimg, srcH1, dir, xin, xout, lop); break;
    default: break;
  }
}
static void cols_pass(int H, float2* buf, int nimg, int bimg,
                      float dir, int xin, int xout, float scale,
                      int sop, float* rdst, int rimg, int lop, hipStream_t st){
  switch (H){
    case 64:   ps_fft_cols<64,16>  <<<dim3(nimg*(64/16)),   512, 0, st>>>(buf, bimg, dir, xin, xout, scale, sop, rdst, rimg, lop); break;
    case 128:  ps_fft_cols<128,16> <<<dim3(nimg*(128/16)),  512, 0, st>>>(buf, bimg, dir, xin, xout, scale, sop, rdst, rimg, lop); break;
    case 256:  ps_fft_cols<256,8>  <<<dim3(nimg*(256/8)),   512, 0, st>>>(buf, bimg, dir, xin, xout, scale, sop, rdst, rimg, lop); break;
    case 512:  ps_fft_cols<512,8>  <<<dim3(nimg*(512/8)),   512, 0, st>>>(buf, bimg, dir, xin, xout, scale, sop, rdst, rimg, lop); break;
    case 1024: ps_fft_cols<1024,4> <<<dim3(nimg*(1024/4)),  512, 0, st>>>(buf, bimg, dir, xin, xout, scale, sop, rdst, rimg, lop); break;
    default: break;
  }
}
static void ac_rows_pass(int H, float* out, const float2* buf, int n_per_img, int nimg,
                         const double* s1, const double* s2, int sstride,
                         double nrecip, float invn2, int base0, int img_mul, int stride,
                         hipStream_t st){
  dim3 g(nimg * 9);
  switch (H){
    case 64:   ps_ac_rows<64>  <<<g, 64,  0, st>>>(out, buf, n_per_img, s1, s2, sstride, nrecip, invn2, base0, img_mul, stride); break;
    case 128:  ps_ac_rows<128> <<<g, 64,  0, st>>>(out, buf, n_per_img, s1, s2, sstride, nrecip, invn2, base0, img_mul, stride); break;
    case 256:  ps_ac_rows<256> <<<g, 128, 0, st>>>(out, buf, n_per_img, s1, s2, sstride, nrecip, invn2, base0, img_mul, stride); break;
    case 512:  ps_ac_rows<512> <<<g, 256, 0, st>>>(out, buf, n_per_img, s1, s2, sstride, nrecip, invn2, base0, img_mul, stride); break;
    case 1024: ps_ac_rows<1024><<<g, 512, 0, st>>>(out, buf, n_per_img, s1, s2, sstride, nrecip, invn2, base0, img_mul, stride); break;
    default: break;
  }
}

static inline dim3 gr(int n){ return dim3((n + 255)/256); }
static inline int  rblocks(int n){ int b = (n + 255)/256; return b > 512 ? 512 : b; }

#define FWD (-1.0f)
#define INV (+1.0f)

extern "C" void kernel_launch(void* const* d_in, const int* in_sizes, int n_in,
                              void* d_out, int out_size, void* d_ws, size_t ws_size,
                              hipStream_t stream){
  (void)in_sizes; (void)n_in;
  const float* im = (const float*)d_in[0];
  float* out = (float*)d_out;

  const int Hs[5]   = {1024, 512, 256, 128, 64};
  const int offs[5] = {0, 256, 384, 448, 480};

  // ---- carve workspace ----
  char* base = (char*)d_ws;
  size_t off = 0;
  auto carve = [&](size_t bytes)->void*{
    void* r = base + off;
    off = (off + bytes + 255) & ~(size_t)255;
    return r;
  };
  float2* lod[5];
  for (int s = 0; s < 5; s++) lod[s] = (float2*)carve((size_t)Hs[s]*Hs[s]*sizeof(float2));
  float2* band[4];
  for (int s = 0; s < 4; s++) band[s] = (float2*)carve((size_t)4*Hs[s]*Hs[s]*sizeof(float2));
  float* recon[5];
  for (int s = 0; s < 5; s++) recon[s] = (float*)carve((size_t)Hs[s]*Hs[s]*sizeof(float));
  float* lp = (float*)carve(128*128*sizeof(float));
  float2* scr  = (float2*)carve((size_t)1024*1024*sizeof(float2));
  float2* scr4 = (float2*)carve((size_t)4*1024*1024*sizeof(float2));
  double* ST = (double*)carve(512*sizeof(double));
  unsigned* MM = (unsigned*)carve(64*sizeof(unsigned));
  if (off > ws_size) return;

  // ---- init ----
  hipMemsetAsync(out, 0, (size_t)out_size*sizeof(float), stream);
  hipMemsetAsync(ST, 0, 512*sizeof(double), stream);
  ps_init_mm<<<1, 1, 0, stream>>>(MM);

  const int n0 = 1024*1024;
  ps_moments<<<rblocks(n0), 256, 0, stream>>>(im, n0, ST + 0);
  ps_minmax <<<rblocks(n0), 256, 0, stream>>>(im, n0, MM);

  // ---- imdft (shifted) ----
  rows_pass(1024, scr, im, nullptr, 0.f, 1, 0, 0, 0, FWD, 0, 512, LOP_R2C, stream);
  cols_pass(1024, scr, 1, 0, FWD, 0, 512, 1.0f, SOP_NONE, nullptr, 0, LOP_NONE, stream);
  ps_mask_hl<<<gr(n0), 256, 0, stream>>>(lod[0], scr, scr);
  rows_pass(1024, scr, scr, nullptr, 0.f, 1, 0, 0, 0, INV, 512, 0, LOP_NONE, stream);
  cols_pass(1024, scr, 1, 0, INV, 512, 0, 1.0f/(float)n0, SOP_NONE, nullptr, 0, LOP_NONE, stream);
  ps_hipass_stats<<<rblocks(n0), 256, 0, stream>>>(scr, n0, ST + 4);

  // ---- pyramid scales ----
  for (int s = 0; s < 4; s++){
    int H = Hs[s], n = H*H;
    float invn = 1.0f/((float)H*(float)H);
    rows_pass(H, scr, lod[s], nullptr, 0.f, 1, 0, 0, 0, INV, H/2, 0, LOP_NONE, stream);
    cols_pass(H, scr, 1, 0, INV, H/2, 0, invn, SOP_REAL, recon[s], 0, LOP_NONE, stream);
    ps_band_mask4<<<gr(n), 256, 0, stream>>>(band[s], lod[s], H, offs[s], -(double)(s+1));
    rows_pass(H, band[s], band[s], nullptr, 0.f, 4, n, n, 0, INV, H/2, 0, LOP_NONE, stream);
    cols_pass(H, band[s], 4, n, INV, H/2, 0, invn, SOP_NONE, nullptr, 0, LOP_NONE, stream);
    ps_crop_lo<<<gr((H/2)*(H/2)), 256, 0, stream>>>(lod[s+1], lod[s], H, offs[s+1], -(double)(s+1));
  }
  rows_pass(64, scr, lod[4], nullptr, 0.f, 1, 0, 0, 0, INV, 32, 0, LOP_NONE, stream);
  cols_pass(64, scr, 1, 0, INV, 32, 0, 1.0f/4096.f, SOP_REAL, recon[4], 0, LOP_NONE, stream);

  // ---- recon moments + autocorrs (cols-first inverse; only 9 rows) ----
  for (int r = 0; r < 5; r++){
    int H = Hs[r], n = H*H;
    float invn = 1.0f/(float)n;
    ps_moments<<<rblocks(n), 256, 0, stream>>>(recon[r], n, ST + 8 + r*4);
    rows_pass(H, scr, recon[r], ST + 8 + r*4, invn, 1, 0, 0, 0, FWD, 0, 0, LOP_CENTER, stream);
    cols_pass(H, scr, 1, 0, FWD, 0, 0, 1.0f, SOP_NONE, nullptr, 0, LOP_NONE, stream);
    cols_pass(H, scr, 1, 0, INV, 0, 0, invn, SOP_NONE, nullptr, 0, LOP_POWER, stream);
    ac_rows_pass(H, out, scr, 0, 1, ST + 8 + r*4, ST + 8 + r*4 + 1, 0,
                 1.0/(double)n, invn, 1330 + r, 0, 5, stream);
  }
  ps_sumabs<<<rblocks(4096), 256, 0, stream>>>(recon[4], 4096, ST + 28);

  // ---- per-scale band Grams ----
  for (int s = 0; s < 4; s++){
    int n = Hs[s]*Hs[s];
    ps_scaleA<<<rblocks(n), 256, 0, stream>>>(band[s], band[s]+n, band[s]+2*n, band[s]+3*n,
                                              n, ST + 64 + s*32);
  }

  // ---- cross-scale ----
  for (int s = 0; s < 3; s++){
    int H1 = Hs[s+1], H2 = Hs[s];
    int n1 = H1*H1, n2 = H2*H2;
    rows_pass(H1, scr, band[s+1], nullptr, 0.f, 4, n1, n1, 0, FWD, 0, H1/2, LOP_NONE, stream);
    cols_pass(H1, scr, 4, n1, FWD, 0, H1/2, 1.0f, SOP_NONE, nullptr, 0, LOP_NONE, stream);
    rows_pass(H2, scr4, scr, nullptr, 0.f, 4, n1, n2, H1, INV, H2/2, 0, LOP_PAD, stream);
    cols_pass(H2, scr4, 4, n2, INV, H2/2, 0, 1.0f/(float)n1, SOP_NONE, nullptr, 0, LOP_NONE, stream);
    ps_scaleB<<<rblocks(n2), 256, 0, stream>>>(scr4, scr4+n2, scr4+2*n2, scr4+3*n2,
                                               band[s], band[s]+n2, band[s]+2*n2, band[s]+3*n2,
                                               n2, ST + 192 + s*80);
  }
  // s=3: expand2(lowpass)
  rows_pass(64, scr, recon[4], nullptr, 0.f, 1, 0, 0, 0, FWD, 0, 32, LOP_R2C, stream);
  cols_pass(64, scr, 1, 0, FWD, 0, 32, 1.0f, SOP_NONE, nullptr, 0, LOP_NONE, stream);
  rows_pass(128, scr4, scr, nullptr, 0.f, 1, 4096, 16384, 64, INV, 64, 0, LOP_PAD, stream);
  cols_pass(128, scr4, 1, 0, INV, 64, 0, 1.0f/4096.f, SOP_REAL, lp, 0, LOP_NONE, stream);
  ps_scaleC<<<rblocks(16384), 256, 0, stream>>>(band[3], band[3]+16384, band[3]+2*16384, band[3]+3*16384,
                                                lp, 16384, ST + 432);

  // ---- band-magnitude autocorrs (batched 4 per scale) ----
  for (int s = 0; s < 4; s++){
    int H = Hs[s], n = H*H;
    float invn = 1.0f/(float)n;
    rows_pass(H, scr4, band[s], ST + 64 + s*32 + 20, invn, 4, n, n, 0, FWD, 0, 0, LOP_ABSC, stream);
    cols_pass(H, scr4, 4, n, FWD, 0, 0, 1.0f, SOP_NONE, nullptr, 0, LOP_NONE, stream);
    cols_pass(H, scr4, 4, n, INV, 0, 0, invn, SOP_NONE, nullptr, 0, LOP_POWER, stream);
    ac_rows_pass(H, out, scr4, n, 4, ST + 64 + s*32 + 20, ST + 64 + s*32 + 28, 1,
                 1.0/(double)n, invn, 24 + s*4, 1, 16, stream);
  }

  // ---- finalize ----
  ps_finalize<<<1, 1, 0, stream>>>(ST, MM, out);
}

// Round 5
// 810.161 us; speedup vs baseline: 10.1500x; 1.2868x over previous
//
#include <hip/hip_runtime.h>
#include <math.h>

#define PI_D 3.14159265358979323846264338327950288

enum { LOP_NONE=0, LOP_R2C, LOP_ABSC, LOP_PAD, LOP_POWDC };
enum { SOP_NONE=0, SOP_REAL, SOP_STATS };

// ---------------------------------------------------------------------------
// helpers
// ---------------------------------------------------------------------------
__host__ __device__ constexpr int P4(int a, int b){ return a*4 - a*(a-1)/2 + (b-a); }
__host__ __device__ constexpr int P5(int a, int b){ return a*5 - a*(a-1)/2 + (b-a); }

__device__ __forceinline__ unsigned encf(float f){
  unsigned u = __float_as_uint(f);
  return (u & 0x80000000u) ? ~u : (u | 0x80000000u);
}
__device__ __forceinline__ float decf(unsigned u){
  unsigned b = (u & 0x80000000u) ? (u ^ 0x80000000u) : ~u;
  return __uint_as_float(b);
}

// wave shuffle-reduce -> LDS -> ONE atomicAdd per counter per block.
template<int CNT, int WAVES>
__device__ __forceinline__ void block_reduce_add(float (&acc)[CNT], double* out){
  __shared__ float red[WAVES*CNT];
  int lane = threadIdx.x & 63;
  int wid  = threadIdx.x >> 6;
  #pragma unroll
  for (int k = 0; k < CNT; k++){
    float v = acc[k];
    #pragma unroll
    for (int o = 32; o > 0; o >>= 1) v += __shfl_down(v, o, 64);
    if (lane == 0) red[wid*CNT + k] = v;
  }
  __syncthreads();
  int t = threadIdx.x;
  if (t < CNT){
    double s = 0.0;
    #pragma unroll
    for (int w = 0; w < WAVES; w++) s += (double)red[w*CNT + t];
    atomicAdd(&out[t], s);
  }
}

// polar grid of the ORIGINAL 1024x1024 image (0-indexed center at 512).
__device__ __forceinline__ void polar_at(int iy, int ix, double& lr, double& ang){
  double yn = (double)(iy - 512) / 512.0;
  double xn = (double)(ix - 512) / 512.0;
  ang = atan2(yn, xn);
  double rad = (iy == 512 && ix == 512) ? (1.0/512.0) : sqrt(xn*xn + yn*yn);
  lr = log2(rad);
}
__device__ __forceinline__ double d_hi(double lr, double shift){
  double v = lr - shift;
  v = fmin(fmax(v, -1.0), 0.0);
  return cos(PI_D * 0.5 * v);
}
__device__ __forceinline__ double d_lo(double lr, double shift){
  double h = d_hi(lr, shift);
  double q = 1.0 - h*h;
  q = fmin(fmax(q, 0.0), 1.0);
  return sqrt(q);
}

// ---------------------------------------------------------------------------
// FFT rows pass: one line per block, out-of-place capable, fused load-op.
// ---------------------------------------------------------------------------
template<int N>
__global__ __launch_bounds__((N/2 < 64) ? 64 : N/2)
void ps_fft_rows(float2* __restrict__ dst, const void* __restrict__ vsrc,
                 const double* __restrict__ msum, float invn,
                 int simg, int dimg, int srcH1,
                 float dir, int xin, int xout, int lop)
{
  constexpr int T = (N/2 < 64) ? 64 : N/2;
  __shared__ float2 smem[2*N];
  float2* sA = smem; float2* sB = smem + N;
  const int t = threadIdx.x;
  const int l = blockIdx.x & (N-1);
  const int img = blockIdx.x / N;
  float2* dline = dst + (size_t)img*(size_t)dimg + (size_t)l*N;

  if (lop == LOP_PAD){
    const int q = N/4;
    const int sl = l - q;
    if (sl < 0 || sl >= srcH1){
      for (int j = t; j < N; j += T) dline[j] = make_float2(0.f, 0.f);
      return;
    }
    const float2* s = (const float2*)vsrc + (size_t)img*simg + (size_t)sl*srcH1;
    for (int j = t; j < N; j += T){
      int p = j ^ xin;
      sA[j] = (p >= q && p < q + srcH1) ? s[p - q] : make_float2(0.f, 0.f);
    }
  } else if (lop == LOP_R2C){
    const float* s = (const float*)vsrc + (size_t)img*simg + (size_t)l*N;
    for (int j = t; j < N; j += T) sA[j] = make_float2(s[j ^ xin], 0.f);
  } else if (lop == LOP_ABSC){
    const float2* s = (const float2*)vsrc + (size_t)img*simg + (size_t)l*N;
    float m = (float)(msum[img] * (double)invn);
    for (int j = t; j < N; j += T){
      float2 v = s[j ^ xin];
      sA[j] = make_float2(sqrtf(v.x*v.x + v.y*v.y) - m, 0.f);
    }
  } else {
    const float2* s = (const float2*)vsrc + (size_t)img*simg + (size_t)l*N;
    for (int j = t; j < N; j += T) sA[j] = s[j ^ xin];
  }
  __syncthreads();
  float2* src = sA; float2* dstp = sB;
  for (int Ns = 1; Ns < N; Ns <<= 1){
    if (t < N/2){
      int k = t & (Ns - 1);
      float2 i0 = src[t], i1 = src[t + N/2];
      float ang = dir * (float)PI_D * (float)k / (float)Ns;
      float sw, cw; __sincosf(ang, &sw, &cw);
      float2 tv = make_float2(cw*i1.x - sw*i1.y, cw*i1.y + sw*i1.x);
      int d = ((t - k) << 1) + k;
      dstp[d]      = make_float2(i0.x + tv.x, i0.y + tv.y);
      dstp[d + Ns] = make_float2(i0.x - tv.x, i0.y - tv.y);
    }
    __syncthreads();
    float2* tmp = src; src = dstp; dstp = tmp;
  }
  for (int j = t; j < N; j += T) dline[j ^ xout] = src[j];
}

// ---------------------------------------------------------------------------
// FFT cols pass: CB adjacent columns per block (coalesced). src/dst may alias.
// lop POWDC: |v|^2 on load with DC bin (src row N/2, col N/2) zeroed.
// fused: FWD fft -> |.|^2 -> INV fft, all in LDS.
// sop: NONE = complex store *scale; REAL = real store *scale; STATS = no store,
//      accumulate 5 moments of (re*scale) into mout.
// ---------------------------------------------------------------------------
template<int N, int CB>
__global__ __launch_bounds__(512)
void ps_fft_cols(float2* __restrict__ dst, const float2* __restrict__ src,
                 int simg, int dimg,
                 float dir, int xin, int xout, float scale,
                 int sop, float* __restrict__ rdst, int rimg,
                 double* __restrict__ mout, int lop, int fused)
{
  constexpr int T = 512;
  constexpr int LCB = (CB==2)?1:(CB==4)?2:(CB==8)?3:4;
  constexpr int NB = N / CB;
  __shared__ float2 smem[2*N*CB];
  float2* sA = smem; float2* sB = smem + N*CB;
  const int t = threadIdx.x;
  const int img = blockIdx.x / NB;
  const int c0 = (blockIdx.x % NB) * CB;
  const float2* sbase = src + (size_t)img*(size_t)simg + c0;
  float2* dbase = dst + (size_t)img*(size_t)dimg + c0;

  for (int e = t; e < N*CB; e += T){
    int j = e >> LCB, c = e & (CB - 1);
    float2 v = sbase[(size_t)(j ^ xin)*N + c];
    if (lop == LOP_POWDC){
      float p = v.x*v.x + v.y*v.y;
      if (((j ^ xin) == N/2) && ((c0 + c) == N/2)) p = 0.f;
      v = make_float2(p, 0.f);
    }
    sA[j*CB + c] = v;
  }
  __syncthreads();
  float2* cur = sA; float2* oth = sB;
  float d1 = fused ? -1.f : dir;
  for (int Ns = 1; Ns < N; Ns <<= 1){
    for (int q = t; q < (N/2)*CB; q += T){
      int c  = q & (CB - 1);
      int tt = q >> LCB;
      int k  = tt & (Ns - 1);
      float2 i0 = cur[tt*CB + c], i1 = cur[(tt + N/2)*CB + c];
      float ang = d1 * (float)PI_D * (float)k / (float)Ns;
      float sw, cw; __sincosf(ang, &sw, &cw);
      float2 tv = make_float2(cw*i1.x - sw*i1.y, cw*i1.y + sw*i1.x);
      int d = ((tt - k) << 1) + k;
      oth[d*CB + c]        = make_float2(i0.x + tv.x, i0.y + tv.y);
      oth[(d + Ns)*CB + c] = make_float2(i0.x - tv.x, i0.y - tv.y);
    }
    __syncthreads();
    float2* tmp = cur; cur = oth; oth = tmp;
  }
  if (fused){
    for (int e = t; e < N*CB; e += T){
      float2 v = cur[e];
      cur[e] = make_float2(v.x*v.x + v.y*v.y, 0.f);
    }
    __syncthreads();
    for (int Ns = 1; Ns < N; Ns <<= 1){
      for (int q = t; q < (N/2)*CB; q += T){
        int c  = q & (CB - 1);
        int tt = q >> LCB;
        int k  = tt & (Ns - 1);
        float2 i0 = cur[tt*CB + c], i1 = cur[(tt + N/2)*CB + c];
        float ang = (float)PI_D * (float)k / (float)Ns;   // inverse
        float sw, cw; __sincosf(ang, &sw, &cw);
        float2 tv = make_float2(cw*i1.x - sw*i1.y, cw*i1.y + sw*i1.x);
        int d = ((tt - k) << 1) + k;
        oth[d*CB + c]        = make_float2(i0.x + tv.x, i0.y + tv.y);
        oth[(d + Ns)*CB + c] = make_float2(i0.x - tv.x, i0.y - tv.y);
      }
      __syncthreads();
      float2* tmp = cur; cur = oth; oth = tmp;
    }
  }
  if (sop == SOP_REAL){
    for (int e = t; e < N*CB; e += T){
      int j = e >> LCB, c = e & (CB - 1);
      rdst[(size_t)img*(size_t)rimg + (size_t)(j ^ xout)*N + c0 + c] = cur[j*CB + c].x * scale;
    }
  } else if (sop == SOP_NONE){
    for (int e = t; e < N*CB; e += T){
      int j = e >> LCB, c = e & (CB - 1);
      float2 v = cur[j*CB + c];
      dbase[(size_t)(j ^ xout)*N + c] = make_float2(v.x*scale, v.y*scale);
    }
  }
  if (mout){
    float acc[5] = {0.f,0.f,0.f,0.f,0.f};
    for (int e = t; e < N*CB; e += T){
      float r = cur[e].x * scale, r2 = r*r;
      acc[0] += r; acc[1] += r2; acc[2] += r2*r; acc[3] += r2*r2; acc[4] += fabsf(r);
    }
    block_reduce_add<5, 8>(acc, mout);
  }
}

// ---------------------------------------------------------------------------
// autocorr tail: inverse-FFT ONLY the 9 needed rows (after full col inverse),
// write the 81 normalized outputs. ctr = E[x^2]-m^2 via Parseval.
// xin: ifftshift XOR on element (x) index of the loaded line.
// ---------------------------------------------------------------------------
template<int N>
__global__ __launch_bounds__((N/2 < 64) ? 64 : N/2)
void ps_ac_rows(float* __restrict__ out, const float2* __restrict__ buf, int n_per_img,
                const double* __restrict__ s1, const double* __restrict__ s2, int sstride,
                double nrecip, float invn2, int base0, int img_mul, int stride, int xin)
{
  constexpr int T = (N/2 < 64) ? 64 : N/2;
  __shared__ float2 smem[2*N];
  float2* sA = smem; float2* sB = smem + N;
  const int t = threadIdx.x;
  const int img = blockIdx.x / 9;
  const int dy  = blockIdx.x % 9;
  const int row = (dy - 4) & (N - 1);
  const float2* line = buf + (size_t)img*(size_t)n_per_img + (size_t)row*N;
  for (int j = t; j < N; j += T) sA[j] = line[j ^ xin];
  __syncthreads();
  float2* src = sA; float2* dstp = sB;
  for (int Ns = 1; Ns < N; Ns <<= 1){
    if (t < N/2){
      int k = t & (Ns - 1);
      float2 i0 = src[t], i1 = src[t + N/2];
      float ang = (float)PI_D * (float)k / (float)Ns;   // inverse
      float sw, cw; __sincosf(ang, &sw, &cw);
      float2 tv = make_float2(cw*i1.x - sw*i1.y, cw*i1.y + sw*i1.x);
      int d = ((t - k) << 1) + k;
      dstp[d]      = make_float2(i0.x + tv.x, i0.y + tv.y);
      dstp[d + Ns] = make_float2(i0.x - tv.x, i0.y - tv.y);
    }
    __syncthreads();
    float2* tmp = src; src = dstp; dstp = tmp;
  }
  if (t < 9){
    int col = (t - 4) & (N - 1);
    double m = s1[img*sstride] * nrecip;
    double ctr = s2[img*sstride] * nrecip - m*m;
    float v = src[col].x * invn2;
    out[base0 + img*img_mul + (dy*9 + t)*stride] = v / ((float)ctr + 1e-12f);
  }
}

// ---------------------------------------------------------------------------
// elementwise kernels
// ---------------------------------------------------------------------------
__global__ __launch_bounds__(256)
void ps_mask_hl(float2* __restrict__ lo_dst, float2* __restrict__ hi_dst,
                const float2* __restrict__ src){
  int i = blockIdx.x*blockDim.x + threadIdx.x;
  if (i >= 1024*1024) return;
  int y = i >> 10, x = i & 1023;
  double lr, ang; polar_at(y, x, lr, ang);
  float2 v = src[i];
  float lo = (float)d_lo(lr, 0.0), hi = (float)d_hi(lr, 0.0);
  lo_dst[i] = make_float2(v.x*lo, v.y*lo);
  hi_dst[i] = make_float2(v.x*hi, v.y*hi);
}
__global__ __launch_bounds__(256)
void ps_band_mask4(float2* __restrict__ dst, const float2* __restrict__ src,
                   int H, int off, double shift){
  int i = blockIdx.x*blockDim.x + threadIdx.x;
  int n = H*H;
  if (i >= n) return;
  int y = i / H, x = i - y*H;
  double lr, ang; polar_at(off + y, off + x, lr, ang);
  double hm = d_hi(lr, shift);
  float2 v = src[i];
  #pragma unroll
  for (int b = 0; b < 4; b++){
    double a0 = ang - PI_D*(double)b/4.0 + PI_D;
    double a = fmod(a0, 2.0*PI_D);
    if (a < 0.0) a += 2.0*PI_D;
    a -= PI_D;
    double mk = 0.0;
    if (fabs(a) < PI_D*0.5){ double c = cos(a); mk = 2.0*sqrt(0.8)*c*c*c; }
    float mf = (float)(hm*mk);
    dst[(size_t)b*n + i] = make_float2(-mf*v.y, mf*v.x);
  }
}
__global__ __launch_bounds__(256)
void ps_crop_lo(float2* dst, const float2* src, int Hs, int offNew, double shift){
  int Hd = Hs/2;
  int i = blockIdx.x*blockDim.x + threadIdx.x;
  if (i >= Hd*Hd) return;
  int y = i / Hd, x = i - y*Hd;
  double lr, ang; polar_at(offNew + y, offNew + x, lr, ang);
  float mk = (float)d_lo(lr, shift);
  float2 v = src[(y + Hs/4)*Hs + (x + Hs/4)];
  dst[i] = make_float2(v.x*mk, v.y*mk);
}

// ---------------------------------------------------------------------------
// reductions
// ---------------------------------------------------------------------------
__global__ void ps_init_mm(unsigned* mm){ mm[0] = 0xFFFFFFFFu; mm[1] = 0u; }

// fused image moments + min/max, float4 vectorized
__global__ __launch_bounds__(256, 1)
void ps_im_stats(const float4* __restrict__ x4, int n4, double* out, unsigned* mm){
  float acc[4] = {0.f,0.f,0.f,0.f};
  float mn = INFINITY, mx = -INFINITY;
  for (int i = blockIdx.x*blockDim.x + threadIdx.x; i < n4; i += gridDim.x*blockDim.x){
    float4 v = x4[i];
    float a0 = v.x, a1 = v.y, a2 = v.z, a3 = v.w;
    acc[0] += a0 + a1 + a2 + a3;
    acc[1] += a0*a0 + a1*a1 + a2*a2 + a3*a3;
    acc[2] += a0*a0*a0 + a1*a1*a1 + a2*a2*a2 + a3*a3*a3;
    acc[3] += a0*a0*a0*a0 + a1*a1*a1*a1 + a2*a2*a2*a2 + a3*a3*a3*a3;
    mn = fminf(mn, fminf(fminf(a0,a1), fminf(a2,a3)));
    mx = fmaxf(mx, fmaxf(fmaxf(a0,a1), fmaxf(a2,a3)));
  }
  block_reduce_add<4, 4>(acc, out);
  #pragma unroll
  for (int o = 32; o > 0; o >>= 1){
    mn = fminf(mn, __shfl_down(mn, o, 64));
    mx = fmaxf(mx, __shfl_down(mx, o, 64));
  }
  if ((threadIdx.x & 63) == 0){
    atomicMin(&mm[0], encf(mn));
    atomicMax(&mm[1], encf(mx));
  }
}
// out: gramM[10], gramR[10], sum|b|[4], sumRe[4], sum|b|^2 diag[4]  (32 total)
__global__ __launch_bounds__(256, 1)
void ps_scaleA(const float2* __restrict__ b0, const float2* __restrict__ b1,
               const float2* __restrict__ b2, const float2* __restrict__ b3,
               int n, double* out){
  float acc[32];
  #pragma unroll
  for (int k = 0; k < 32; k++) acc[k] = 0.f;
  for (int i = blockIdx.x*blockDim.x + threadIdx.x; i < n; i += gridDim.x*blockDim.x){
    float2 v0 = b0[i], v1 = b1[i], v2 = b2[i], v3 = b3[i];
    float ab[4] = { sqrtf(v0.x*v0.x+v0.y*v0.y), sqrtf(v1.x*v1.x+v1.y*v1.y),
                    sqrtf(v2.x*v2.x+v2.y*v2.y), sqrtf(v3.x*v3.x+v3.y*v3.y) };
    float re[4] = { v0.x, v1.x, v2.x, v3.x };
    #pragma unroll
    for (int a = 0; a < 4; a++){
      #pragma unroll
      for (int c = a; c < 4; c++){
        acc[P4(a,c)]      += ab[a]*ab[c];
        acc[10 + P4(a,c)] += re[a]*re[c];
      }
      acc[20 + a] += ab[a];
      acc[24 + a] += re[a];
      acc[28 + a] += ab[a]*ab[a];
    }
  }
  block_reduce_add<32, 4>(acc, out);
}
__global__ __launch_bounds__(256, 1)
void ps_scaleB(const float2* __restrict__ u0, const float2* __restrict__ u1,
               const float2* __restrict__ u2, const float2* __restrict__ u3,
               const float2* __restrict__ s0, const float2* __restrict__ s1,
               const float2* __restrict__ s2, const float2* __restrict__ s3,
               int n, double* out){
  float acc[72];
  #pragma unroll
  for (int k = 0; k < 72; k++) acc[k] = 0.f;
  for (int i = blockIdx.x*blockDim.x + threadIdx.x; i < n; i += gridDim.x*blockDim.x){
    float2 u[4] = { u0[i], u1[i], u2[i], u3[i] };
    float2 bb[4] = { s0[i], s1[i], s2[i], s3[i] };
    float au[4], dre[4], dim[4], M[4], R[4];
    #pragma unroll
    for (int c = 0; c < 4; c++){
      float xx = u[c].x, yy = u[c].y;
      float mag = sqrtf(xx*xx + yy*yy);
      float den = mag + 1e-12f;
      au[c] = mag;
      dre[c] = (xx*xx - yy*yy)/den;
      dim[c] = (2.f*xx*yy)/den;
      M[c] = sqrtf(bb[c].x*bb[c].x + bb[c].y*bb[c].y);
      R[c] = bb[c].x;
    }
    #pragma unroll
    for (int c = 0; c < 4; c++){
      acc[c]      += au[c];
      acc[4 + c]  += au[c]*au[c];
      acc[24 + c] += dre[c];
      acc[28 + c] += dim[c];
      acc[32 + c] += dre[c]*dre[c];
      acc[36 + c] += dim[c]*dim[c];
    }
    #pragma unroll
    for (int a = 0; a < 4; a++)
      #pragma unroll
      for (int c = 0; c < 4; c++){
        acc[8 + a*4 + c]  += M[a]*au[c];
        acc[40 + a*4 + c] += R[a]*dre[c];
        acc[56 + a*4 + c] += R[a]*dim[c];
      }
  }
  block_reduce_add<72, 4>(acc, out);
}
__global__ __launch_bounds__(256, 1)
void ps_scaleC(const float2* __restrict__ s0, const float2* __restrict__ s1,
               const float2* __restrict__ s2, const float2* __restrict__ s3,
               const float* __restrict__ lp, int n, double* out){
  float acc[36];
  #pragma unroll
  for (int k = 0; k < 36; k++) acc[k] = 0.f;
  for (int i = blockIdx.x*blockDim.x + threadIdx.x; i < n; i += gridDim.x*blockDim.x){
    int y = i >> 7, x = i & 127;
    float L[5];
    L[0] = lp[i];
    L[1] = lp[(y << 7) | ((x + 126) & 127)];
    L[2] = lp[(y << 7) | ((x + 2) & 127)];
    L[3] = lp[(((y + 126) & 127) << 7) | x];
    L[4] = lp[(((y + 2) & 127) << 7) | x];
    float R[4] = { s0[i].x, s1[i].x, s2[i].x, s3[i].x };
    acc[0] += L[0];
    #pragma unroll
    for (int a = 0; a < 5; a++)
      #pragma unroll
      for (int c = a; c < 5; c++)
        acc[1 + P5(a,c)] += L[a]*L[c];
    #pragma unroll
    for (int a = 0; a < 4; a++)
      #pragma unroll
      for (int j = 0; j < 5; j++)
        acc[16 + a*5 + j] += R[a]*L[j];
  }
  block_reduce_add<36, 4>(acc, out);
}

// ---------------------------------------------------------------------------
// finalize (single thread, doubles). ST layout:
//  [0..3] image moments; [4..8] hipass s1,s2,s3,s4,sabs
//  [10+r*6 .. 14+r*6] recon r: s1,s2,s3,s4,sabs (r=0..4)
//  [64+s*32] scaleA(32); [192+s*80] scaleB(72); [432..467] scaleC(36)
// ---------------------------------------------------------------------------
__global__ void ps_finalize(const double* __restrict__ ST, const unsigned* __restrict__ MM,
                            float* __restrict__ out){
  if (threadIdx.x != 0 || blockIdx.x != 0) return;
  const double n0 = 1048576.0;
  {
    double m = ST[0]/n0, e2 = ST[1]/n0, e3 = ST[2]/n0, e4 = ST[3]/n0;
    double v = e2 - m*m;
    double c3 = e3 - 3.0*m*e2 + 2.0*m*m*m;
    double c4 = e4 - 4.0*m*e3 + 6.0*m*m*e2 - 3.0*m*m*m*m;
    out[0] = (float)m; out[1] = (float)v;
    out[2] = (float)(c3/pow(v,1.5)); out[3] = (float)(c4/(v*v));
    out[4] = decf(MM[0]); out[5] = decf(MM[1]);
    out[6] = (float)(ST[8]/n0);                               // mean|hipass|
    out[23] = (float)(ST[10 + 4*6 + 4]/4096.0);               // mean|lowpass|
    out[2460] = (float)(ST[5]/n0 - (ST[4]/n0)*(ST[4]/n0));    // var_hp
  }
  for (int s = 0; s < 4; s++){
    double ns = (double)(1024 >> s) * (double)(1024 >> s);
    for (int b = 0; b < 4; b++)
      out[7 + s*4 + b] = (float)(ST[64 + s*32 + 20 + b]/ns);
  }
  for (int r = 0; r < 5; r++){
    double nr = (double)(1024 >> r) * (double)(1024 >> r);
    if (r == 4) nr = 4096.0;
    const double* Mo = ST + 10 + r*6;
    double m = Mo[0]/nr, e2 = Mo[1]/nr, e3 = Mo[2]/nr, e4 = Mo[3]/nr;
    double v = e2 - m*m;
    double c3 = e3 - 3.0*m*e2 + 2.0*m*m*m;
    double c4 = e4 - 4.0*m*e3 + 6.0*m*m*e2 - 3.0*m*m*m*m;
    out[1320 + r] = (float)(c3/pow(v,1.5));
    out[1325 + r] = (float)(c4/(v*v));
    out[1735 + r] = (float)sqrt(v);
  }
  for (int s = 0; s < 4; s++){
    double ns = (double)(1024 >> s) * (double)(1024 >> s);
    const double* A = ST + 64 + s*32;
    double mM[4], mR[4], sdM[4], sdR[4], cM[4][4], cR[4][4];
    for (int a = 0; a < 4; a++){ mM[a] = A[20+a]/ns; mR[a] = A[24+a]/ns; }
    for (int a = 0; a < 4; a++)
      for (int b = a; b < 4; b++){
        double vM = A[P4(a,b)]/ns - mM[a]*mM[b];
        double vR = A[10 + P4(a,b)]/ns - mR[a]*mR[b];
        cM[a][b] = cM[b][a] = vM;
        cR[a][b] = cR[b][a] = vR;
      }
    for (int a = 0; a < 4; a++){ sdM[a] = sqrt(cM[a][a]); sdR[a] = sqrt(cR[a][a]); }
    for (int a = 0; a < 4; a++)
      for (int b = 0; b < 4; b++){
        out[1740 + (a*4 + b)*5 + s] = (float)(cM[a][b]/(sdM[a]*sdM[b] + 1e-12));
        out[1884 + (a*8 + b)*5 + s] = (float)(cR[a][b]/(sdR[a]*sdR[b] + 1e-12));
      }
    if (s < 3){
      const double* B = ST + 192 + s*80;
      double mU[4], sdU[4], mdr[4], mdi[4], sdr[4], sdi[4];
      for (int c = 0; c < 4; c++){
        mU[c] = B[c]/ns;       sdU[c] = sqrt(B[4+c]/ns - mU[c]*mU[c]);
        mdr[c] = B[24+c]/ns;   mdi[c] = B[28+c]/ns;
        sdr[c] = sqrt(B[32+c]/ns - mdr[c]*mdr[c]);
        sdi[c] = sqrt(B[36+c]/ns - mdi[c]*mdi[c]);
      }
      for (int a = 0; a < 4; a++)
        for (int c = 0; c < 4; c++){
          out[1820 + (a*4 + c)*4 + s] =
            (float)((B[8 + a*4 + c]/ns - mM[a]*mU[c])/(sdM[a]*sdU[c] + 1e-12));
          out[2204 + (a*8 + c)*4 + s] =
            (float)((B[40 + a*4 + c]/ns - mR[a]*mdr[c])/(sdR[a]*sdr[c] + 1e-12));
          out[2204 + (a*8 + 4 + c)*4 + s] =
            (float)((B[56 + a*4 + c]/ns - mR[a]*mdi[c])/(sdR[a]*sdi[c] + 1e-12));
        }
    } else {
      const double* C = ST + 432;
      const double n3 = 16384.0;
      double lb = C[0]/n3;
      double cL[5][5], sdL[5];
      for (int i = 0; i < 5; i++)
        for (int j = i; j < 5; j++){
          double v = C[1 + P5(i,j)]/n3 - lb*lb;
          cL[i][j] = cL[j][i] = v;
        }
      for (int i = 0; i < 5; i++) sdL[i] = sqrt(cL[i][i]);
      for (int a = 0; a < 4; a++)
        for (int j = 0; j < 5; j++)
          out[2204 + (a*8 + j)*4 + 3] =
            (float)((C[16 + a*5 + j]/n3 - mR[a]*lb)/(sdR[a]*sdL[j] + 1e-12));
      for (int i = 0; i < 5; i++)
        for (int j = 0; j < 5; j++)
          out[1884 + (i*8 + j)*5 + 4] = (float)(cL[i][j]/(sdL[i]*sdL[j] + 1e-12));
    }
  }
}

// ---------------------------------------------------------------------------
// host orchestration
// ---------------------------------------------------------------------------
static void rows_pass(int H, float2* dst, const void* src,
                      const double* msum, float invn,
                      int nimg, int simg, int dimg, int srcH1,
                      float dir, int xin, int xout, int lop, hipStream_t st){
  dim3 g(nimg * H);
  switch (H){
    case 64:   ps_fft_rows<64>  <<<g, 64,  0, st>>>(dst, src, msum, invn, simg, dimg, srcH1, dir, xin, xout, lop); break;
    case 128:  ps_fft_rows<128> <<<g, 64,  0, st>>>(dst, src, msum, invn, simg, dimg, srcH1, dir, xin, xout, lop); break;
    case 256:  ps_fft_rows<256> <<<g, 128, 0, st>>>(dst, src, msum, invn, simg, dimg, srcH1, dir, xin, xout, lop); break;
    case 512:  ps_fft_rows<512> <<<g, 256, 0, st>>>(dst, src, msum, invn, simg, dimg, srcH1, dir, xin, xout, lop); break;
    case 1024: ps_fft_rows<1024><<<g, 512, 0, st>>>(dst, src, msum, invn, simg, dimg, srcH1, dir, xin, xout, lop); break;
    default: break;
  }
}
static void cols_pass(int H, float2* dst, const float2* src, int nimg, int simg, int dimg,
                      float dir, int xin, int xout, float scale,
                      int sop, float* rdst, int rimg, double* mout,
                      int lop, int fused, hipStream_t st){
  switch (H){
    case 64:   ps_fft_cols<64,16>  <<<dim3(nimg*(64/16)),  512, 0, st>>>(dst, src, simg, dimg, dir, xin, xout, scale, sop, rdst, rimg, mout, lop, fused); break;
    case 128:  ps_fft_cols<128,16> <<<dim3(nimg*(128/16)), 512, 0, st>>>(dst, src, simg, dimg, dir, xin, xout, scale, sop, rdst, rimg, mout, lop, fused); break;
    case 256:  ps_fft_cols<256,8>  <<<dim3(nimg*(256/8)),  512, 0, st>>>(dst, src, simg, dimg, dir, xin, xout, scale, sop, rdst, rimg, mout, lop, fused); break;
    case 512:  ps_fft_cols<512,8>  <<<dim3(nimg*(512/8)),  512, 0, st>>>(dst, src, simg, dimg, dir, xin, xout, scale, sop, rdst, rimg, mout, lop, fused); break;
    case 1024: ps_fft_cols<1024,4> <<<dim3(nimg*(1024/4)), 512, 0, st>>>(dst, src, simg, dimg, dir, xin, xout, scale, sop, rdst, rimg, mout, lop, fused); break;
    default: break;
  }
}
static void ac_rows_pass(int H, float* out, const float2* buf, int n_per_img, int nimg,
                         const double* s1, const double* s2, int sstride,
                         double nrecip, float invn2, int base0, int img_mul, int stride,
                         int xin, hipStream_t st){
  dim3 g(nimg * 9);
  switch (H){
    case 64:   ps_ac_rows<64>  <<<g, 64,  0, st>>>(out, buf, n_per_img, s1, s2, sstride, nrecip, invn2, base0, img_mul, stride, xin); break;
    case 128:  ps_ac_rows<128> <<<g, 64,  0, st>>>(out, buf, n_per_img, s1, s2, sstride, nrecip, invn2, base0, img_mul, stride, xin); break;
    case 256:  ps_ac_rows<256> <<<g, 128, 0, st>>>(out, buf, n_per_img, s1, s2, sstride, nrecip, invn2, base0, img_mul, stride, xin); break;
    case 512:  ps_ac_rows<512> <<<g, 256, 0, st>>>(out, buf, n_per_img, s1, s2, sstride, nrecip, invn2, base0, img_mul, stride, xin); break;
    case 1024: ps_ac_rows<1024><<<g, 512, 0, st>>>(out, buf, n_per_img, s1, s2, sstride, nrecip, invn2, base0, img_mul, stride, xin); break;
    default: break;
  }
}

static inline dim3 gr(int n){ return dim3((n + 255)/256); }
static inline int  rblocks(int n){ int b = (n + 255)/256; return b > 512 ? 512 : b; }

#define FWD (-1.0f)
#define INV (+1.0f)

extern "C" void kernel_launch(void* const* d_in, const int* in_sizes, int n_in,
                              void* d_out, int out_size, void* d_ws, size_t ws_size,
                              hipStream_t stream){
  (void)in_sizes; (void)n_in;
  const float* im = (const float*)d_in[0];
  float* out = (float*)d_out;

  const int Hs[5]   = {1024, 512, 256, 128, 64};
  const int offs[5] = {0, 256, 384, 448, 480};

  // ---- carve workspace ----
  char* base = (char*)d_ws;
  size_t off = 0;
  auto carve = [&](size_t bytes)->void*{
    void* r = base + off;
    off = (off + bytes + 255) & ~(size_t)255;
    return r;
  };
  float2* lod[5];
  for (int s = 0; s < 5; s++) lod[s] = (float2*)carve((size_t)Hs[s]*Hs[s]*sizeof(float2));
  float2* band[4];
  for (int s = 0; s < 4; s++) band[s] = (float2*)carve((size_t)4*Hs[s]*Hs[s]*sizeof(float2));
  float2* bdft[4];           // band DFTs kept for cross-scale expand (s=1..3)
  bdft[0] = nullptr;
  for (int s = 1; s < 4; s++) bdft[s] = (float2*)carve((size_t)4*Hs[s]*Hs[s]*sizeof(float2));
  float* lp = (float*)carve(128*128*sizeof(float));
  float2* scr  = (float2*)carve((size_t)1024*1024*sizeof(float2));
  float2* scr4 = (float2*)carve((size_t)4*1024*1024*sizeof(float2));
  double* ST = (double*)carve(512*sizeof(double));
  unsigned* MM = (unsigned*)carve(64*sizeof(unsigned));
  if (off > ws_size) return;

  // ---- init ----
  hipMemsetAsync(out, 0, (size_t)out_size*sizeof(float), stream);
  hipMemsetAsync(ST, 0, 512*sizeof(double), stream);
  ps_init_mm<<<1, 1, 0, stream>>>(MM);

  const int n0 = 1024*1024;
  ps_im_stats<<<256, 256, 0, stream>>>((const float4*)im, n0/4, ST + 0, MM);

  // ---- imdft (shifted) ----
  rows_pass(1024, scr, im, nullptr, 0.f, 1, 0, 0, 0, FWD, 0, 512, LOP_R2C, stream);
  cols_pass(1024, scr, scr, 1, 0, 0, FWD, 0, 512, 1.0f, SOP_NONE, nullptr, 0, nullptr, LOP_NONE, 0, stream);
  ps_mask_hl<<<gr(n0), 256, 0, stream>>>(lod[0], scr, scr);
  // hipass stats (no spatial store)
  rows_pass(1024, scr, scr, nullptr, 0.f, 1, 0, 0, 0, INV, 512, 0, LOP_NONE, stream);
  cols_pass(1024, scr, scr, 1, 0, 0, INV, 512, 0, 1.0f/(float)n0, SOP_STATS, nullptr, 0, ST + 4, LOP_NONE, 0, stream);

  // ---- pyramid scales ----
  for (int s = 0; s < 4; s++){
    int H = Hs[s], n = H*H;
    float invn = 1.0f/((float)H*(float)H);
    // recon stats (no spatial store)
    rows_pass(H, scr, lod[s], nullptr, 0.f, 1, 0, 0, 0, INV, H/2, 0, LOP_NONE, stream);
    cols_pass(H, scr, scr, 1, 0, 0, INV, H/2, 0, invn, SOP_STATS, nullptr, 0, ST + 10 + s*6, LOP_NONE, 0, stream);
    // band DFTs -> spatial bands (keep DFTs for s>=1)
    float2* bq = (s == 0) ? scr4 : bdft[s];
    ps_band_mask4<<<gr(n), 256, 0, stream>>>(bq, lod[s], H, offs[s], -(double)(s+1));
    rows_pass(H, band[s], bq, nullptr, 0.f, 4, n, n, 0, INV, H/2, 0, LOP_NONE, stream);
    cols_pass(H, band[s], band[s], 4, n, n, INV, H/2, 0, invn, SOP_NONE, nullptr, 0, nullptr, LOP_NONE, 0, stream);
    ps_crop_lo<<<gr((H/2)*(H/2)), 256, 0, stream>>>(lod[s+1], lod[s], H, offs[s+1], -(double)(s+1));
  }
  // lowpass stats
  rows_pass(64, scr, lod[4], nullptr, 0.f, 1, 0, 0, 0, INV, 32, 0, LOP_NONE, stream);
  cols_pass(64, scr, scr, 1, 0, 0, INV, 32, 0, 1.0f/4096.f, SOP_STATS, nullptr, 0, ST + 10 + 4*6, LOP_NONE, 0, stream);

  // ---- recon autocorrs straight from lod (power spectrum, DC zeroed) ----
  for (int r = 0; r < 5; r++){
    int H = Hs[r], n = H*H;
    float invn = 1.0f/(float)n;
    cols_pass(H, scr, lod[r], 1, n, n, INV, H/2, 0, invn, SOP_NONE, nullptr, 0, nullptr, LOP_POWDC, 0, stream);
    ac_rows_pass(H, out, scr, 0, 1, ST + 10 + r*6, ST + 10 + r*6 + 1, 0,
                 1.0/(double)n, invn, 1330 + r, 0, 5, H/2, stream);
  }

  // ---- per-scale band Grams ----
  for (int s = 0; s < 4; s++){
    int n = Hs[s]*Hs[s];
    ps_scaleA<<<rblocks(n), 256, 0, stream>>>(band[s], band[s]+n, band[s]+2*n, band[s]+3*n,
                                              n, ST + 64 + s*32);
  }

  // ---- cross-scale: pad kept band DFTs directly (no forward FFT) ----
  for (int s = 0; s < 3; s++){
    int H1 = Hs[s+1], H2 = Hs[s];
    int n1 = H1*H1, n2 = H2*H2;
    rows_pass(H2, scr4, bdft[s+1], nullptr, 0.f, 4, n1, n2, H1, INV, H2/2, 0, LOP_PAD, stream);
    cols_pass(H2, scr4, scr4, 4, n2, n2, INV, H2/2, 0, 1.0f/(float)n1, SOP_NONE, nullptr, 0, nullptr, LOP_NONE, 0, stream);
    ps_scaleB<<<rblocks(n2), 256, 0, stream>>>(scr4, scr4+n2, scr4+2*n2, scr4+3*n2,
                                               band[s], band[s]+n2, band[s]+2*n2, band[s]+3*n2,
                                               n2, ST + 192 + s*80);
  }
  // s=3: expand2(lowpass) = pad lod[4] directly
  rows_pass(128, scr4, lod[4], nullptr, 0.f, 1, 4096, 16384, 64, INV, 64, 0, LOP_PAD, stream);
  cols_pass(128, scr4, scr4, 1, 16384, 16384, INV, 64, 0, 1.0f/4096.f, SOP_REAL, lp, 0, nullptr, LOP_NONE, 0, stream);
  ps_scaleC<<<rblocks(16384), 256, 0, stream>>>(band[3], band[3]+16384, band[3]+2*16384, band[3]+3*16384,
                                                lp, 16384, ST + 432);

  // ---- band-magnitude autocorrs (fused FWD->|.|^2->INV col pass) ----
  for (int s = 0; s < 4; s++){
    int H = Hs[s], n = H*H;
    float invn = 1.0f/(float)n;
    rows_pass(H, scr4, band[s], ST + 64 + s*32 + 20, invn, 4, n, n, 0, FWD, 0, 0, LOP_ABSC, stream);
    cols_pass(H, scr4, scr4, 4, n, n, FWD, 0, 0, invn, SOP_NONE, nullptr, 0, nullptr, LOP_NONE, 1, stream);
    ac_rows_pass(H, out, scr4, n, 4, ST + 64 + s*32 + 20, ST + 64 + s*32 + 28, 1,
                 1.0/(double)n, invn, 24 + s*4, 1, 16, 0, stream);
  }

  // ---- finalize ----
  ps_finalize<<<1, 1, 0, stream>>>(ST, MM, out);
}